// Round 1
// 6899.805 us; speedup vs baseline: 1.0450x; 1.0450x over previous
//
#include <hip/hip_runtime.h>
#include <hip/hip_bf16.h>

typedef __hip_bfloat16 bf16;
typedef __attribute__((ext_vector_type(4))) float f32x4;
typedef __attribute__((ext_vector_type(8))) short bf16x8;

#define B_ 64
#define T_ 250
#define D_ 768
#define H_ 12
#define DH_ 64
#define F_ 32
#define L_ 12
#define BT_ (B_*T_)   // 16000
#define NF_ (H_*F_)   // 384
#define QKVN_ (3*D_)  // 2304

// ---------------- lengths (mask dtype autodetect: int32 / float32 / bool8) ----------------
__global__ void lengths_kernel(const unsigned char* __restrict__ mask, int* __restrict__ lengths) {
    __shared__ int not_i32, not_f32;
    const unsigned int* w = (const unsigned int*)mask;
    int tid = threadIdx.x;
    if (tid == 0) { not_i32 = 0; not_f32 = 0; }
    __syncthreads();
    int li = 0, lf = 0;
    for (int i = tid; i < 4000; i += 256) {
        unsigned int v = w[i];
        if (v > 1u) li = 1;
        if (v != 0u && v != 0x3F800000u) lf = 1;
    }
    if (li) not_i32 = 1;
    if (lf) not_f32 = 1;
    __syncthreads();
    int mode = (!not_i32) ? 0 : ((!not_f32) ? 1 : 2);
    if (tid < B_) {
        int cnt = 0;
        if (mode == 0) {
            const int* r = (const int*)mask + tid * T_;
            for (int t = 0; t < T_; ++t) cnt += (r[t] != 0);
        } else if (mode == 1) {
            const unsigned int* r = w + tid * T_;
            for (int t = 0; t < T_; ++t) cnt += (r[t] != 0);
        } else {
            const unsigned char* r = mask + tid * T_;
            for (int t = 0; t < T_; ++t) cnt += (r[t] != 0);
        }
        lengths[tid] = cnt;
    }
}

// ---------------- embedding: x f32 + xb bf16 shadow ----------------
__global__ void embed_kernel(const int* __restrict__ batch, const float* __restrict__ tok,
                             const float* __restrict__ pos, float* __restrict__ x,
                             bf16* __restrict__ xb) {
    int bt = blockIdx.x;
    int t = bt % T_;
    int tok_id = batch[bt];
    const float* tr = tok + (size_t)tok_id * D_;
    const float* pr = pos + (size_t)t * D_;
    float* xr = x + (size_t)bt * D_;
    bf16* xbr = xb + (size_t)bt * D_;
    for (int d = threadIdx.x; d < D_; d += 256) {
        float v = tr[d] + pr[d];
        xr[d] = v;
        xbr[d] = __float2bfloat16(v);
    }
}

// ---------------- per-layer weight transpose+cast: W f32 [K,N] -> Wt bf16 [N,K] ----------------
__global__ __launch_bounds__(256) void transpose_w(
    const float* __restrict__ Wq, const float* __restrict__ Wk, const float* __restrict__ Wv,
    const float* __restrict__ Wo, const float* __restrict__ W1, const float* __restrict__ W2,
    int l, bf16* __restrict__ Wt)
{
    __shared__ float tile[32][33];
    int m = blockIdx.z;
    const float* src;
    switch (m) {
        case 0: src = Wq; break; case 1: src = Wk; break; case 2: src = Wv; break;
        case 3: src = Wo; break; case 4: src = W1; break; default: src = W2; break;
    }
    src += (size_t)l * D_ * D_;
    bf16* dst = Wt + (size_t)m * D_ * D_;
    int k0 = blockIdx.y * 32, n0 = blockIdx.x * 32;
    int tx = threadIdx.x, ty = threadIdx.y;
#pragma unroll
    for (int i = 0; i < 4; ++i)
        tile[ty + i * 8][tx] = src[(size_t)(k0 + ty + i * 8) * D_ + n0 + tx];
    __syncthreads();
#pragma unroll
    for (int i = 0; i < 4; ++i)
        dst[(size_t)(n0 + ty + i * 8) * D_ + k0 + tx] = __float2bfloat16(tile[tx][ty + i * 8]);
}

// ---------------- block-diagonal omega^T: WomT[n=h*32+f][k] = (k/64==h) ? om[k%64][f] : 0 ----------------
__global__ void build_wom(const float* __restrict__ om, bf16* __restrict__ wt) {
    int o = blockIdx.x * 256 + threadIdx.x;     // n*768 + k
    if (o >= NF_ * D_) return;
    int n = o / D_, k = o - n * D_;
    float v = ((k >> 6) == (n >> 5)) ? om[(k & 63) * F_ + (n & 31)] : 0.f;
    wt[o] = __float2bfloat16(v);
}

// ---------------- pack qkv bias: qkvb[l][0..2304) = [bq[l] ; bk[l] ; bv[l]] ----------------
__global__ void pack_bias(const float* __restrict__ bq, const float* __restrict__ bk,
                          const float* __restrict__ bv, float* __restrict__ qkvb) {
    int o = blockIdx.x * 256 + threadIdx.x;
    if (o >= L_ * QKVN_) return;
    int l = o / QKVN_, c = o - l * QKVN_;
    float v;
    if (c < D_) v = bq[l * D_ + c];
    else if (c < 2 * D_) v = bk[l * D_ + c - D_];
    else v = bv[l * D_ + c - 2 * D_];
    qkvb[o] = v;
}

// ---------------- MFMA GEMM: C[16000,N] = A[16000,768] @ Bt[N,768]^T + bias, epilogue acts ----------------
// A has row stride lda, C has row stride ldc (enables column-slice views of a wide buffer).
// act: 0 = none, 1 = exact GELU, 2 = relu, 3 = relu + prefix-length mask (rows are bt)
__global__ __launch_bounds__(256) void gemm_bt(
    const bf16* __restrict__ A, const bf16* __restrict__ Bt,
    const float* __restrict__ bias, bf16* __restrict__ C,
    int N, int lda, int ldc, int act, const int* __restrict__ lengths)
{
    const int K = D_;
    __shared__ __attribute__((aligned(16))) short As[128 * 32];
    __shared__ __attribute__((aligned(16))) short Bs[128 * 32];
    const int tid = threadIdx.x;
    const int lane = tid & 63, wave = tid >> 6;
    const int row0 = blockIdx.y * 128, col0 = blockIdx.x * 128;
    const int wm = (wave >> 1) * 64, wn = (wave & 1) * 64;

    f32x4 acc[4][4];
#pragma unroll
    for (int i = 0; i < 4; ++i)
#pragma unroll
        for (int j = 0; j < 4; ++j) acc[i][j] = (f32x4){0.f, 0.f, 0.f, 0.f};

    const int srow = lane >> 2;            // 0..15
    const int scol = (lane & 3) * 8;       // element offset within 32
    const short* Ag = (const short*)A + (size_t)(row0 + srow) * lda + scol;
    const short* Bg = (const short*)Bt + (size_t)(col0 + srow) * K + scol;

    for (int k0 = 0; k0 < K; k0 += 32) {
#pragma unroll
        for (int c = 0; c < 2; ++c) {
            int cc = wave * 2 + c;
            __builtin_amdgcn_global_load_lds(
                (const __attribute__((address_space(1))) unsigned int*)(Ag + (size_t)cc * 16 * lda + k0),
                (__attribute__((address_space(3))) unsigned int*)(As + cc * 512), 16, 0, 0);
            __builtin_amdgcn_global_load_lds(
                (const __attribute__((address_space(1))) unsigned int*)(Bg + (size_t)cc * 16 * K + k0),
                (__attribute__((address_space(3))) unsigned int*)(Bs + cc * 512), 16, 0, 0);
        }
        __syncthreads();
        bf16x8 af[4], bfr[4];
#pragma unroll
        for (int mi = 0; mi < 4; ++mi)
            af[mi] = *(const bf16x8*)(As + ((wm + mi * 16 + (lane & 15)) << 5) + ((lane >> 4) << 3));
#pragma unroll
        for (int ni = 0; ni < 4; ++ni)
            bfr[ni] = *(const bf16x8*)(Bs + ((wn + ni * 16 + (lane & 15)) << 5) + ((lane >> 4) << 3));
#pragma unroll
        for (int mi = 0; mi < 4; ++mi)
#pragma unroll
            for (int ni = 0; ni < 4; ++ni)
                acc[mi][ni] = __builtin_amdgcn_mfma_f32_16x16x32_bf16(af[mi], bfr[ni], acc[mi][ni], 0, 0, 0);
        __syncthreads();
    }

    float bj[4];
#pragma unroll
    for (int ni = 0; ni < 4; ++ni) {
        int col = col0 + wn + ni * 16 + (lane & 15);
        bj[ni] = bias ? bias[col] : 0.f;
    }
#pragma unroll
    for (int mi = 0; mi < 4; ++mi) {
#pragma unroll
        for (int r = 0; r < 4; ++r) {
            int row = row0 + wm + mi * 16 + ((lane >> 4) << 2) + r;
            bool kill = false;
            if (act == 3) { int b = row / T_; int t = row - b * T_; kill = (t >= lengths[b]); }
            size_t base = (size_t)row * ldc + col0 + wn + (lane & 15);
#pragma unroll
            for (int ni = 0; ni < 4; ++ni) {
                float v = acc[mi][ni][r] + bj[ni];
                if (act == 1) v = 0.5f * v * (1.0f + erff(v * 0.70710678118654752f));
                else if (act >= 2) v = fmaxf(v, 0.f);
                if (kill) v = 0.f;
                C[base + ni * 16] = __float2bfloat16(v);
            }
        }
    }
}

// ---------------- Ksum[b,h,f] = sum_s Kf[b,s,h,f] ----------------
__global__ void ksum_kernel(const bf16* __restrict__ Kf, float* __restrict__ Ksum) {
    int o = blockIdx.x * 256 + threadIdx.x;   // (b,h,f)
    if (o >= B_ * H_ * F_) return;
    int f = o & (F_ - 1);
    int h = (o >> 5) % H_;
    int b = o / (H_ * F_);
    float s = 0.f;
    for (int t = 0; t < T_; ++t)
        s += __bfloat162float(Kf[((size_t)(b * T_ + t) * H_ + h) * F_ + f]);
    Ksum[o] = s;
}

// ---------------- KV[b,h,f,m] = sum_s Kf[b,s,h,f] * v[b,s,h*64+m] (v row stride ldv) ----------------
__global__ void kv_kernel(const bf16* __restrict__ Kf, const bf16* __restrict__ v, int ldv,
                          float* __restrict__ KV) {
    int o = blockIdx.x * 256 + threadIdx.x;   // (b,h,f,m)
    if (o >= B_ * H_ * F_ * DH_) return;
    int m = o & (DH_ - 1);
    int f = (o >> 6) & (F_ - 1);
    int h = (o >> 11) % H_;
    int b = o / (H_ * F_ * DH_);
    float acc = 0.f;
    for (int s = 0; s < T_; ++s)
        acc += __bfloat162float(Kf[((size_t)(b * T_ + s) * H_ + h) * F_ + f])
             * __bfloat162float(v[(size_t)(b * T_ + s) * ldv + h * DH_ + m]);
    KV[o] = acc;
}

// ---------------- attn out: out[bt, h*64+m] = Z * sum_f Qf*KV ; Z stored (out row stride ldo) ----------------
__global__ void attn_out_kernel(const bf16* __restrict__ Qf, const float* __restrict__ KV,
                                const float* __restrict__ Ksum, float* __restrict__ Z,
                                bf16* __restrict__ out, int ldo) {
    int o = blockIdx.x * 256 + threadIdx.x;   // (bt, h, m)
    if (o >= BT_ * D_) return;
    int m = o & (DH_ - 1);
    int h = (o >> 6) % H_;
    int bt = o / D_;
    int b = bt / T_;
    const bf16* qf = Qf + ((size_t)bt * H_ + h) * F_;
    const float* ks = Ksum + ((size_t)b * H_ + h) * F_;
    const float* kv = KV + ((size_t)b * H_ + h) * F_ * DH_;
    float zden = 1e-6f, acc = 0.f;
#pragma unroll
    for (int f = 0; f < F_; ++f) {
        float q = __bfloat162float(qf[f]);
        zden += q * ks[f];
        acc += q * kv[f * DH_ + m];
    }
    float z = 1.0f / zden;
    if (m == 0) Z[(size_t)bt * H_ + h] = z;
    out[(size_t)bt * ldo + h * DH_ + m] = __float2bfloat16(acc * z);
}

// ---------------- attn weights via MFMA: w[b,h,t,s] = Z[b,t,h] * sum_f Qf[b,t,h,f]*Kf[b,s,h,f] ----------------
// grid (4 t-tiles, B*H); 4 waves/block, wave w owns s-tile w. No LDS: F=32 is one MFMA K-step,
// Qf/Kf fragments loaded straight from global (L1/L2-resident 4KB tiles).
__global__ __launch_bounds__(256) void attnw_kernel(const bf16* __restrict__ Qf,
                                                    const bf16* __restrict__ Kf,
                                                    const float* __restrict__ Z,
                                                    float* __restrict__ out) {
    int tt = blockIdx.x;            // t-tile 0..3
    int bh = blockIdx.y;            // b*H+h
    int b = bh / H_, h = bh - b * H_;
    int tid = threadIdx.x;
    int lane = tid & 63, w = tid >> 6;
    int t0 = tt * 64, s0 = w * 64;
    int kof = (lane >> 4) * 8;      // k-slice within F=32

    const short* Qs = (const short*)Qf;
    const short* Ks = (const short*)Kf;

    bf16x8 af[4], bfr[4];
#pragma unroll
    for (int mi = 0; mi < 4; ++mi) {
        int t = t0 + mi * 16 + (lane & 15);
        if (t > T_ - 1) t = T_ - 1;                       // clamp: garbage rows never stored
        af[mi] = *(const bf16x8*)(Qs + ((size_t)(b * T_ + t) * H_ + h) * F_ + kof);
    }
#pragma unroll
    for (int ni = 0; ni < 4; ++ni) {
        int s = s0 + ni * 16 + (lane & 15);
        if (s > T_ - 1) s = T_ - 1;
        bfr[ni] = *(const bf16x8*)(Ks + ((size_t)(b * T_ + s) * H_ + h) * F_ + kof);
    }

    f32x4 acc[4][4];
#pragma unroll
    for (int i = 0; i < 4; ++i)
#pragma unroll
        for (int j = 0; j < 4; ++j) acc[i][j] = (f32x4){0.f, 0.f, 0.f, 0.f};
#pragma unroll
    for (int mi = 0; mi < 4; ++mi)
#pragma unroll
        for (int ni = 0; ni < 4; ++ni)
            acc[mi][ni] = __builtin_amdgcn_mfma_f32_16x16x32_bf16(af[mi], bfr[ni], acc[mi][ni], 0, 0, 0);

    // C/D layout: col(s) = lane&15, row(t) = (lane>>4)*4 + r  [m89/m91]
#pragma unroll
    for (int mi = 0; mi < 4; ++mi) {
#pragma unroll
        for (int r = 0; r < 4; ++r) {
            int t = t0 + mi * 16 + (lane >> 4) * 4 + r;
            if (t >= T_) continue;
            float z = Z[(size_t)(b * T_ + t) * H_ + h];
            size_t base = ((size_t)bh * T_ + t) * T_;
#pragma unroll
            for (int ni = 0; ni < 4; ++ni) {
                int s = s0 + ni * 16 + (lane & 15);
                if (s < T_) out[base + s] = acc[mi][ni][r] * z;
            }
        }
    }
}

// ---------------- x = LN(x + res); res has row stride ldr; writes f32 x and bf16 xb ----------------
__global__ __launch_bounds__(256) void ln_kernel(float* __restrict__ x, const bf16* __restrict__ res,
                                                 int ldr,
                                                 const float* __restrict__ g, const float* __restrict__ bb,
                                                 bf16* __restrict__ xb) {
    int bt = blockIdx.x, tid = threadIdx.x;
    float* xr = x + (size_t)bt * D_;
    const bf16* rr = res + (size_t)bt * ldr;
    float v[3]; float s = 0.f, ss = 0.f;
#pragma unroll
    for (int i = 0; i < 3; ++i) {
        int idx = tid + i * 256;
        float t = xr[idx] + __bfloat162float(rr[idx]);
        v[i] = t; s += t; ss += t * t;
    }
#pragma unroll
    for (int o = 1; o < 64; o <<= 1) { s += __shfl_xor(s, o, 64); ss += __shfl_xor(ss, o, 64); }
    __shared__ float red[4][2];
    int wave = tid >> 6, lane = tid & 63;
    if (lane == 0) { red[wave][0] = s; red[wave][1] = ss; }
    __syncthreads();
    s = red[0][0] + red[1][0] + red[2][0] + red[3][0];
    ss = red[0][1] + red[1][1] + red[2][1] + red[3][1];
    float mean = s * (1.f / D_);
    float var = ss * (1.f / D_) - mean * mean;
    float rstd = rsqrtf(var + 1e-5f);
    bf16* xbr = xb + (size_t)bt * D_;
#pragma unroll
    for (int i = 0; i < 3; ++i) {
        int idx = tid + i * 256;
        float o = (v[i] - mean) * rstd * g[idx] + bb[idx];
        xr[idx] = o;
        xbr[idx] = __float2bfloat16(o);
    }
}

// ---------------- CLS writeout ----------------
__global__ void cls_kernel(const float* __restrict__ x, float* __restrict__ out) {
    int o = blockIdx.x * 256 + threadIdx.x;
    if (o >= B_ * D_) return;
    int b = o / D_, d = o % D_;
    out[o] = x[(size_t)(b * T_) * D_ + d];
}

extern "C" void kernel_launch(void* const* d_in, const int* in_sizes, int n_in,
                              void* d_out, int out_size, void* d_ws, size_t ws_size,
                              hipStream_t stream) {
    const int*   batch = (const int*)d_in[0];
    const unsigned char* mask = (const unsigned char*)d_in[1];
    const float* tok  = (const float*)d_in[2];
    const float* pos  = (const float*)d_in[3];
    const float* Wq   = (const float*)d_in[4];
    const float* bq   = (const float*)d_in[5];
    const float* Wk   = (const float*)d_in[6];
    const float* bk   = (const float*)d_in[7];
    const float* Wv   = (const float*)d_in[8];
    const float* bv   = (const float*)d_in[9];
    const float* Wo   = (const float*)d_in[10];
    const float* bo   = (const float*)d_in[11];
    const float* omega= (const float*)d_in[12];
    const float* ln1g = (const float*)d_in[13];
    const float* ln1b = (const float*)d_in[14];
    const float* ln2g = (const float*)d_in[15];
    const float* ln2b = (const float*)d_in[16];
    const float* W1   = (const float*)d_in[17];
    const float* b1   = (const float*)d_in[18];
    const float* W2   = (const float*)d_in[19];
    const float* b2   = (const float*)d_in[20];

    float* out_cls  = (float*)d_out;                   // [B, D]
    float* out_attn = (float*)d_out + B_ * D_;         // [B, H, T, T]

    // workspace layout (~162 MB). qkv [BT,2304] holds column-slices:
    //   [0,768): q  -> later attn-out        -> later FFN2 out (ln2 res)
    //   [768,1536): k -> later Wo-proj out (ln1 res)
    //   [1536,2304): v -> later FFN1 mid (GELU)
    char* wsb = (char*)d_ws;
    float* x   = (float*)wsb; wsb += (size_t)BT_ * D_ * 4;        // 49.2 MB
    bf16* xb   = (bf16*)wsb;  wsb += (size_t)BT_ * D_ * 2;        // 24.6 MB
    bf16* qkv  = (bf16*)wsb;  wsb += (size_t)BT_ * QKVN_ * 2;     // 73.7 MB
    bf16* Qf   = (bf16*)wsb;  wsb += (size_t)BT_ * NF_ * 2;       // 12.3 MB
    bf16* Kf   = (bf16*)wsb;  wsb += (size_t)BT_ * NF_ * 2;
    float* KV  = (float*)wsb; wsb += (size_t)B_ * H_ * F_ * DH_ * 4;
    float* Ksum= (float*)wsb; wsb += (size_t)B_ * H_ * F_ * 4;
    float* Z   = (float*)wsb; wsb += (size_t)BT_ * H_ * 4;
    bf16* Wt   = (bf16*)wsb;  wsb += (size_t)6 * D_ * D_ * 2;     // 7.1 MB, reused per layer
    bf16* WomT = (bf16*)wsb;  wsb += (size_t)NF_ * D_ * 2;        // 0.6 MB
    float* qkvb= (float*)wsb; wsb += (size_t)L_ * QKVN_ * 4;      // 110 KB
    int* lengths = (int*)wsb; wsb += 256;

    lengths_kernel<<<1, 256, 0, stream>>>(mask, lengths);
    embed_kernel<<<BT_, 256, 0, stream>>>(batch, tok, pos, x, xb);
    pack_bias<<<(L_ * QKVN_ + 255) / 256, 256, 0, stream>>>(bq, bk, bv, qkvb);

    dim3 qkv_g(QKVN_ / 128, BT_ / 128);   // (18, 125)
    dim3 gemm_g(D_ / 128, BT_ / 128);     // (6, 125)
    dim3 feat_g(NF_ / 128, BT_ / 128);    // (3, 125)
    dim3 tr_g(24, 24, 6);
    dim3 tr_b(32, 8);
    const size_t WS = (size_t)D_ * D_;

    for (int l = 0; l < L_; ++l) {
        transpose_w<<<tr_g, tr_b, 0, stream>>>(Wq, Wk, Wv, Wo, W1, W2, l, Wt);
        build_wom<<<(NF_ * D_ + 255) / 256, 256, 0, stream>>>(omega + (size_t)l * DH_ * F_, WomT);

        // fused QKV: [BT,768] @ [2304,768]^T -> qkv [BT,2304]
        gemm_bt<<<qkv_g, 256, 0, stream>>>(xb, Wt, qkvb + l * QKVN_, qkv,
                                           QKVN_, D_, QKVN_, 0, lengths);

        // features: Qf = relu(q @ omT), Kf = relu(k @ omT) masked
        gemm_bt<<<feat_g, 256, 0, stream>>>(qkv, WomT, nullptr, Qf,
                                            NF_, QKVN_, NF_, 2, lengths);
        gemm_bt<<<feat_g, 256, 0, stream>>>(qkv + D_, WomT, nullptr, Kf,
                                            NF_, QKVN_, NF_, 3, lengths);

        ksum_kernel<<<(B_ * H_ * F_ + 255) / 256, 256, 0, stream>>>(Kf, Ksum);
        kv_kernel<<<(B_ * H_ * F_ * DH_ + 255) / 256, 256, 0, stream>>>(Kf, qkv + 2 * D_, QKVN_, KV);
        // attn out written into qkv cols [0,768) (q slice is dead after Qf)
        attn_out_kernel<<<(BT_ * D_ + 255) / 256, 256, 0, stream>>>(Qf, KV, Ksum, Z, qkv, QKVN_);

        if (l == L_ - 1)
            attnw_kernel<<<dim3(4, B_ * H_), 256, 0, stream>>>(Qf, Kf, Z, out_attn);

        // Wo proj: reads qkv[:,0:768), writes qkv[:,768:1536) (k slice dead)
        gemm_bt<<<gemm_g, 256, 0, stream>>>(qkv, Wt + 3 * WS, bo + l * D_, qkv + D_,
                                            D_, QKVN_, QKVN_, 0, lengths);
        ln_kernel<<<BT_, 256, 0, stream>>>(x, qkv + D_, QKVN_, ln1g + l * D_, ln1b + l * D_, xb);

        // FFN1 (GELU): xb @ W1 -> qkv[:,1536:2304) (v slice dead)
        gemm_bt<<<gemm_g, 256, 0, stream>>>(xb, Wt + 4 * WS, b1 + l * D_, qkv + 2 * D_,
                                            D_, D_, QKVN_, 1, lengths);
        // FFN2: qkv[:,1536:2304) @ W2 -> qkv[:,0:768)
        gemm_bt<<<gemm_g, 256, 0, stream>>>(qkv + 2 * D_, Wt + 5 * WS, b2 + l * D_, qkv,
                                            D_, QKVN_, QKVN_, 0, lengths);
        ln_kernel<<<BT_, 256, 0, stream>>>(x, qkv, QKVN_, ln2g + l * D_, ln2b + l * D_, xb);
    }

    cls_kernel<<<(B_ * D_ + 255) / 256, 256, 0, stream>>>(x, out_cls);
}

// Round 2
// 4887.342 us; speedup vs baseline: 1.4753x; 1.4118x over previous
//
#include <hip/hip_runtime.h>
#include <hip/hip_bf16.h>

typedef __hip_bfloat16 bf16;
typedef __attribute__((ext_vector_type(4))) float f32x4;
typedef __attribute__((ext_vector_type(8))) short bf16x8;
typedef __attribute__((ext_vector_type(4))) short short4v;

#define B_ 64
#define T_ 250
#define D_ 768
#define H_ 12
#define DH_ 64
#define F_ 32
#define L_ 12
#define BT_ (B_*T_)   // 16000
#define NF_ (H_*F_)   // 384
#define QKVN_ (3*D_)  // 2304

static __device__ __forceinline__ float b2f(short s) {
    union { float f; unsigned u; } z; z.u = ((unsigned)(unsigned short)s) << 16; return z.f;
}
static __device__ __forceinline__ short f2bs(float f) {
    bf16 b = __float2bfloat16(f);
    return *(short*)&b;
}

// ---------------- lengths (mask dtype autodetect: int32 / float32 / bool8) ----------------
__global__ void lengths_kernel(const unsigned char* __restrict__ mask, int* __restrict__ lengths) {
    __shared__ int not_i32, not_f32;
    const unsigned int* w = (const unsigned int*)mask;
    int tid = threadIdx.x;
    if (tid == 0) { not_i32 = 0; not_f32 = 0; }
    __syncthreads();
    int li = 0, lf = 0;
    for (int i = tid; i < 4000; i += 256) {
        unsigned int v = w[i];
        if (v > 1u) li = 1;
        if (v != 0u && v != 0x3F800000u) lf = 1;
    }
    if (li) not_i32 = 1;
    if (lf) not_f32 = 1;
    __syncthreads();
    int mode = (!not_i32) ? 0 : ((!not_f32) ? 1 : 2);
    if (tid < B_) {
        int cnt = 0;
        if (mode == 0) {
            const int* r = (const int*)mask + tid * T_;
            for (int t = 0; t < T_; ++t) cnt += (r[t] != 0);
        } else if (mode == 1) {
            const unsigned int* r = w + tid * T_;
            for (int t = 0; t < T_; ++t) cnt += (r[t] != 0);
        } else {
            const unsigned char* r = mask + tid * T_;
            for (int t = 0; t < T_; ++t) cnt += (r[t] != 0);
        }
        lengths[tid] = cnt;
    }
}

// ---------------- embedding: x f32 + xb bf16 shadow ----------------
__global__ void embed_kernel(const int* __restrict__ batch, const float* __restrict__ tok,
                             const float* __restrict__ pos, float* __restrict__ x,
                             bf16* __restrict__ xb) {
    int bt = blockIdx.x;
    int t = bt % T_;
    int tok_id = batch[bt];
    const float* tr = tok + (size_t)tok_id * D_;
    const float* pr = pos + (size_t)t * D_;
    float* xr = x + (size_t)bt * D_;
    bf16* xbr = xb + (size_t)bt * D_;
    for (int d = threadIdx.x; d < D_; d += 256) {
        float v = tr[d] + pr[d];
        xr[d] = v;
        xbr[d] = __float2bfloat16(v);
    }
}

// ---------------- per-layer weight transpose+cast: W f32 [K,N] -> Wt bf16 [N,K] ----------------
__global__ __launch_bounds__(256) void transpose_w(
    const float* __restrict__ Wq, const float* __restrict__ Wk, const float* __restrict__ Wv,
    const float* __restrict__ Wo, const float* __restrict__ W1, const float* __restrict__ W2,
    int l, bf16* __restrict__ Wt)
{
    __shared__ float tile[32][33];
    int m = blockIdx.z;
    const float* src;
    switch (m) {
        case 0: src = Wq; break; case 1: src = Wk; break; case 2: src = Wv; break;
        case 3: src = Wo; break; case 4: src = W1; break; default: src = W2; break;
    }
    src += (size_t)l * D_ * D_;
    bf16* dst = Wt + (size_t)m * D_ * D_;
    int k0 = blockIdx.y * 32, n0 = blockIdx.x * 32;
    int tx = threadIdx.x, ty = threadIdx.y;
#pragma unroll
    for (int i = 0; i < 4; ++i)
        tile[ty + i * 8][tx] = src[(size_t)(k0 + ty + i * 8) * D_ + n0 + tx];
    __syncthreads();
#pragma unroll
    for (int i = 0; i < 4; ++i)
        dst[(size_t)(n0 + ty + i * 8) * D_ + k0 + tx] = __float2bfloat16(tile[tx][ty + i * 8]);
}

// ---------------- pack qkv bias: qkvb[l][0..2304) = [bq[l] ; bk[l] ; bv[l]] ----------------
__global__ void pack_bias(const float* __restrict__ bq, const float* __restrict__ bk,
                          const float* __restrict__ bv, float* __restrict__ qkvb) {
    int o = blockIdx.x * 256 + threadIdx.x;
    if (o >= L_ * QKVN_) return;
    int l = o / QKVN_, c = o - l * QKVN_;
    float v;
    if (c < D_) v = bq[l * D_ + c];
    else if (c < 2 * D_) v = bk[l * D_ + c - D_];
    else v = bv[l * D_ + c - 2 * D_];
    qkvb[o] = v;
}

// ---------------- MFMA GEMM: C[16000,N] = A[16000,768] @ Bt[N,768]^T + bias, epilogue acts ----------------
// act: 0 = none, 1 = exact GELU, 2 = relu, 3 = relu + prefix-length mask (rows are bt)
__global__ __launch_bounds__(256) void gemm_bt(
    const bf16* __restrict__ A, const bf16* __restrict__ Bt,
    const float* __restrict__ bias, bf16* __restrict__ C,
    int N, int lda, int ldc, int act, const int* __restrict__ lengths)
{
    const int K = D_;
    __shared__ __attribute__((aligned(16))) short As[128 * 32];
    __shared__ __attribute__((aligned(16))) short Bs[128 * 32];
    const int tid = threadIdx.x;
    const int lane = tid & 63, wave = tid >> 6;
    const int row0 = blockIdx.y * 128, col0 = blockIdx.x * 128;
    const int wm = (wave >> 1) * 64, wn = (wave & 1) * 64;

    f32x4 acc[4][4];
#pragma unroll
    for (int i = 0; i < 4; ++i)
#pragma unroll
        for (int j = 0; j < 4; ++j) acc[i][j] = (f32x4){0.f, 0.f, 0.f, 0.f};

    const int srow = lane >> 2;            // 0..15
    const int scol = (lane & 3) * 8;       // element offset within 32
    const short* Ag = (const short*)A + (size_t)(row0 + srow) * lda + scol;
    const short* Bg = (const short*)Bt + (size_t)(col0 + srow) * K + scol;

    for (int k0 = 0; k0 < K; k0 += 32) {
#pragma unroll
        for (int c = 0; c < 2; ++c) {
            int cc = wave * 2 + c;
            __builtin_amdgcn_global_load_lds(
                (const __attribute__((address_space(1))) unsigned int*)(Ag + (size_t)cc * 16 * lda + k0),
                (__attribute__((address_space(3))) unsigned int*)(As + cc * 512), 16, 0, 0);
            __builtin_amdgcn_global_load_lds(
                (const __attribute__((address_space(1))) unsigned int*)(Bg + (size_t)cc * 16 * K + k0),
                (__attribute__((address_space(3))) unsigned int*)(Bs + cc * 512), 16, 0, 0);
        }
        __syncthreads();
        bf16x8 af[4], bfr[4];
#pragma unroll
        for (int mi = 0; mi < 4; ++mi)
            af[mi] = *(const bf16x8*)(As + ((wm + mi * 16 + (lane & 15)) << 5) + ((lane >> 4) << 3));
#pragma unroll
        for (int ni = 0; ni < 4; ++ni)
            bfr[ni] = *(const bf16x8*)(Bs + ((wn + ni * 16 + (lane & 15)) << 5) + ((lane >> 4) << 3));
#pragma unroll
        for (int mi = 0; mi < 4; ++mi)
#pragma unroll
            for (int ni = 0; ni < 4; ++ni)
                acc[mi][ni] = __builtin_amdgcn_mfma_f32_16x16x32_bf16(af[mi], bfr[ni], acc[mi][ni], 0, 0, 0);
        __syncthreads();
    }

    float bj[4];
#pragma unroll
    for (int ni = 0; ni < 4; ++ni) {
        int col = col0 + wn + ni * 16 + (lane & 15);
        bj[ni] = bias ? bias[col] : 0.f;
    }
#pragma unroll
    for (int mi = 0; mi < 4; ++mi) {
#pragma unroll
        for (int r = 0; r < 4; ++r) {
            int row = row0 + wm + mi * 16 + ((lane >> 4) << 2) + r;
            bool kill = false;
            if (act == 3) { int b = row / T_; int t = row - b * T_; kill = (t >= lengths[b]); }
            size_t base = (size_t)row * ldc + col0 + wn + (lane & 15);
#pragma unroll
            for (int ni = 0; ni < 4; ++ni) {
                float v = acc[mi][ni][r] + bj[ni];
                if (act == 1) v = 0.5f * v * (1.0f + erff(v * 0.70710678118654752f));
                else if (act >= 2) v = fmaxf(v, 0.f);
                if (kill) v = 0.f;
                C[base + ni * 16] = __float2bfloat16(v);
            }
        }
    }
}

// ---------------- features via MFMA, K=64 (block-diag omega): Qf/Kf[bt, h*32+f] ----------------
// grid (BT/128, H, 2); z=0: Qf=relu(q@om), z=1: Kf=relu(k@om) + prefix mask
__global__ __launch_bounds__(256) void feat_kernel(
    const bf16* __restrict__ qkv, const float* __restrict__ om,
    bf16* __restrict__ Qf, bf16* __restrict__ Kf, const int* __restrict__ lengths)
{
    __shared__ __attribute__((aligned(16))) short omT[32 * 64];   // [f][k]
    int z = blockIdx.z, h = blockIdx.y;
    int row0 = blockIdx.x * 128;
    int tid = threadIdx.x, lane = tid & 63, wave = tid >> 6;
    {
        int f = tid >> 3, k0 = (tid & 7) * 8;
#pragma unroll
        for (int j = 0; j < 8; ++j)
            omT[f * 64 + k0 + j] = f2bs(om[(size_t)(k0 + j) * F_ + f]);
    }
    __syncthreads();

    const short* A = (const short*)qkv + (size_t)z * D_ + h * DH_;
    int rsel = lane & 15, kof = (lane >> 4) << 3;

    bf16x8 af[2][2], bfr[2][2];
#pragma unroll
    for (int mi = 0; mi < 2; ++mi) {
        int row = row0 + wave * 32 + mi * 16 + rsel;
#pragma unroll
        for (int ks = 0; ks < 2; ++ks)
            af[mi][ks] = *(const bf16x8*)(A + (size_t)row * QKVN_ + ks * 32 + kof);
    }
#pragma unroll
    for (int ni = 0; ni < 2; ++ni)
#pragma unroll
        for (int ks = 0; ks < 2; ++ks)
            bfr[ni][ks] = *(const bf16x8*)(omT + (ni * 16 + rsel) * 64 + ks * 32 + kof);

    f32x4 acc[2][2];
#pragma unroll
    for (int i = 0; i < 2; ++i)
#pragma unroll
        for (int j = 0; j < 2; ++j) acc[i][j] = (f32x4){0.f, 0.f, 0.f, 0.f};
#pragma unroll
    for (int mi = 0; mi < 2; ++mi)
#pragma unroll
        for (int ni = 0; ni < 2; ++ni)
#pragma unroll
            for (int ks = 0; ks < 2; ++ks)
                acc[mi][ni] = __builtin_amdgcn_mfma_f32_16x16x32_bf16(af[mi][ks], bfr[ni][ks], acc[mi][ni], 0, 0, 0);

    bf16* out = z ? Kf : Qf;
#pragma unroll
    for (int mi = 0; mi < 2; ++mi) {
#pragma unroll
        for (int r = 0; r < 4; ++r) {
            int row = row0 + wave * 32 + mi * 16 + ((lane >> 4) << 2) + r;
            bool kill = false;
            if (z) { int b = row / T_; int t = row - b * T_; kill = (t >= lengths[b]); }
#pragma unroll
            for (int ni = 0; ni < 2; ++ni) {
                float v = fmaxf(acc[mi][ni][r], 0.f);
                if (kill) v = 0.f;
                out[(size_t)row * NF_ + h * F_ + ni * 16 + rsel] = __float2bfloat16(v);
            }
        }
    }
}

// ---------------- fused KV + Ksum via MFMA: one block per (b,h) ----------------
// KV[b,h,f,m] = sum_s Kf[b,s,h,f]*v[b,s,h,m];  Ksum[b,h,f] = sum_s Kf[b,s,h,f]
__global__ __launch_bounds__(256) void kvsum_kernel(
    const bf16* __restrict__ Kf, const bf16* __restrict__ v, int ldv,
    float* __restrict__ KV, float* __restrict__ Ksum)
{
    __shared__ short KfS[64][36];    // [s][f], row stride 36 shorts (b64-aligned, groups split banks)
    __shared__ short vS[64][68];     // [s][m]
    int h = blockIdx.x, b = blockIdx.y;
    int tid = threadIdx.x, lane = tid & 63, wv = tid >> 6;
    int lr = tid >> 2, cp = tid & 3;

    const short* Kg = (const short*)Kf + (size_t)(b * T_) * NF_ + h * F_;
    const short* Vg = (const short*)v + (size_t)(b * T_) * ldv + h * DH_;

    f32x4 acc[2];
    acc[0] = (f32x4){0.f, 0.f, 0.f, 0.f};
    acc[1] = (f32x4){0.f, 0.f, 0.f, 0.f};
    float ksacc = 0.f;

    for (int s0 = 0; s0 < T_; s0 += 64) {
        __syncthreads();
        int s = s0 + lr;
        if (s < T_) {
            bf16x8 k8 = *(const bf16x8*)(Kg + (size_t)s * NF_ + cp * 8);
            *(short4v*)&KfS[lr][cp * 8]     = *((const short4v*)&k8);
            *(short4v*)&KfS[lr][cp * 8 + 4] = *((const short4v*)&k8 + 1);
            bf16x8 v8a = *(const bf16x8*)(Vg + (size_t)s * ldv + cp * 16);
            bf16x8 v8b = *(const bf16x8*)(Vg + (size_t)s * ldv + cp * 16 + 8);
            *(short4v*)&vS[lr][cp * 16]      = *((const short4v*)&v8a);
            *(short4v*)&vS[lr][cp * 16 + 4]  = *((const short4v*)&v8a + 1);
            *(short4v*)&vS[lr][cp * 16 + 8]  = *((const short4v*)&v8b);
            *(short4v*)&vS[lr][cp * 16 + 12] = *((const short4v*)&v8b + 1);
        } else {
            short4v zz = (short4v){0, 0, 0, 0};
            *(short4v*)&KfS[lr][cp * 8]     = zz;
            *(short4v*)&KfS[lr][cp * 8 + 4] = zz;
            *(short4v*)&vS[lr][cp * 16]      = zz;
            *(short4v*)&vS[lr][cp * 16 + 4]  = zz;
            *(short4v*)&vS[lr][cp * 16 + 8]  = zz;
            *(short4v*)&vS[lr][cp * 16 + 12] = zz;
        }
        __syncthreads();
        if (tid < 32) {        // Ksum on wave 0 lanes 0..31 (f = tid)
            float p0 = 0.f, p1 = 0.f;
            for (int ss = 0; ss < 64; ss += 2) {
                p0 += b2f(KfS[ss][tid]);
                p1 += b2f(KfS[ss + 1][tid]);
            }
            ksacc += p0 + p1;
        }
        // transpose-gather fragments: A = Kf^T [f][s], B^T = v^T [m][s]
        bf16x8 af0[2], af1[2], bfr[2];
#pragma unroll
        for (int ks = 0; ks < 2; ++ks) {
            int sb = ks * 32 + ((lane >> 4) << 3);
#pragma unroll
            for (int j = 0; j < 8; ++j) {
                ((short*)&af0[ks])[j] = KfS[sb + j][lane & 15];
                ((short*)&af1[ks])[j] = KfS[sb + j][16 + (lane & 15)];
                ((short*)&bfr[ks])[j] = vS[sb + j][wv * 16 + (lane & 15)];
            }
        }
#pragma unroll
        for (int ks = 0; ks < 2; ++ks) {
            acc[0] = __builtin_amdgcn_mfma_f32_16x16x32_bf16(af0[ks], bfr[ks], acc[0], 0, 0, 0);
            acc[1] = __builtin_amdgcn_mfma_f32_16x16x32_bf16(af1[ks], bfr[ks], acc[1], 0, 0, 0);
        }
    }

    int m = wv * 16 + (lane & 15);
#pragma unroll
    for (int mi = 0; mi < 2; ++mi) {
#pragma unroll
        for (int r = 0; r < 4; ++r) {
            int f = mi * 16 + ((lane >> 4) << 2) + r;
            KV[((size_t)(b * H_ + h) * F_ + f) * DH_ + m] = acc[mi][r];
        }
    }
    if (tid < 32) Ksum[(size_t)(b * H_ + h) * F_ + tid] = ksacc;
}

// ---------------- attn out: out[bt, h*64+m] = Z * sum_f Qf*KV ; Z stored (out row stride ldo) ----------------
__global__ void attn_out_kernel(const bf16* __restrict__ Qf, const float* __restrict__ KV,
                                const float* __restrict__ Ksum, float* __restrict__ Z,
                                bf16* __restrict__ out, int ldo) {
    int o = blockIdx.x * 256 + threadIdx.x;   // (bt, h, m)
    if (o >= BT_ * D_) return;
    int m = o & (DH_ - 1);
    int h = (o >> 6) % H_;
    int bt = o / D_;
    int b = bt / T_;
    const bf16* qf = Qf + ((size_t)bt * H_ + h) * F_;
    const float* ks = Ksum + ((size_t)b * H_ + h) * F_;
    const float* kv = KV + ((size_t)b * H_ + h) * F_ * DH_;
    float zden = 1e-6f, acc = 0.f;
#pragma unroll
    for (int f = 0; f < F_; ++f) {
        float q = __bfloat162float(qf[f]);
        zden += q * ks[f];
        acc += q * kv[f * DH_ + m];
    }
    float z = 1.0f / zden;
    if (m == 0) Z[(size_t)bt * H_ + h] = z;
    out[(size_t)bt * ldo + h * DH_ + m] = __float2bfloat16(acc * z);
}

// ---------------- attn weights via MFMA: w[b,h,t,s] = Z[b,t,h] * sum_f Qf*Kf ----------------
__global__ __launch_bounds__(256) void attnw_kernel(const bf16* __restrict__ Qf,
                                                    const bf16* __restrict__ Kf,
                                                    const float* __restrict__ Z,
                                                    float* __restrict__ out) {
    int tt = blockIdx.x;            // t-tile 0..3
    int bh = blockIdx.y;            // b*H+h
    int b = bh / H_, h = bh - b * H_;
    int tid = threadIdx.x;
    int lane = tid & 63, w = tid >> 6;
    int t0 = tt * 64, s0 = w * 64;
    int kof = (lane >> 4) * 8;

    const short* Qs = (const short*)Qf;
    const short* Ks = (const short*)Kf;

    bf16x8 af[4], bfr[4];
#pragma unroll
    for (int mi = 0; mi < 4; ++mi) {
        int t = t0 + mi * 16 + (lane & 15);
        if (t > T_ - 1) t = T_ - 1;
        af[mi] = *(const bf16x8*)(Qs + ((size_t)(b * T_ + t) * H_ + h) * F_ + kof);
    }
#pragma unroll
    for (int ni = 0; ni < 4; ++ni) {
        int s = s0 + ni * 16 + (lane & 15);
        if (s > T_ - 1) s = T_ - 1;
        bfr[ni] = *(const bf16x8*)(Ks + ((size_t)(b * T_ + s) * H_ + h) * F_ + kof);
    }

    f32x4 acc[4][4];
#pragma unroll
    for (int i = 0; i < 4; ++i)
#pragma unroll
        for (int j = 0; j < 4; ++j) acc[i][j] = (f32x4){0.f, 0.f, 0.f, 0.f};
#pragma unroll
    for (int mi = 0; mi < 4; ++mi)
#pragma unroll
        for (int ni = 0; ni < 4; ++ni)
            acc[mi][ni] = __builtin_amdgcn_mfma_f32_16x16x32_bf16(af[mi], bfr[ni], acc[mi][ni], 0, 0, 0);

#pragma unroll
    for (int mi = 0; mi < 4; ++mi) {
#pragma unroll
        for (int r = 0; r < 4; ++r) {
            int t = t0 + mi * 16 + (lane >> 4) * 4 + r;
            if (t >= T_) continue;
            float z = Z[(size_t)(b * T_ + t) * H_ + h];
            size_t base = ((size_t)bh * T_ + t) * T_;
#pragma unroll
            for (int ni = 0; ni < 4; ++ni) {
                int s = s0 + ni * 16 + (lane & 15);
                if (s < T_) out[base + s] = acc[mi][ni][r] * z;
            }
        }
    }
}

// ---------------- x = LN(x + res); res has row stride ldr; writes f32 x and bf16 xb ----------------
__global__ __launch_bounds__(256) void ln_kernel(float* __restrict__ x, const bf16* __restrict__ res,
                                                 int ldr,
                                                 const float* __restrict__ g, const float* __restrict__ bb,
                                                 bf16* __restrict__ xb) {
    int bt = blockIdx.x, tid = threadIdx.x;
    float* xr = x + (size_t)bt * D_;
    const bf16* rr = res + (size_t)bt * ldr;
    float v[3]; float s = 0.f, ss = 0.f;
#pragma unroll
    for (int i = 0; i < 3; ++i) {
        int idx = tid + i * 256;
        float t = xr[idx] + __bfloat162float(rr[idx]);
        v[i] = t; s += t; ss += t * t;
    }
#pragma unroll
    for (int o = 1; o < 64; o <<= 1) { s += __shfl_xor(s, o, 64); ss += __shfl_xor(ss, o, 64); }
    __shared__ float red[4][2];
    int wave = tid >> 6, lane = tid & 63;
    if (lane == 0) { red[wave][0] = s; red[wave][1] = ss; }
    __syncthreads();
    s = red[0][0] + red[1][0] + red[2][0] + red[3][0];
    ss = red[0][1] + red[1][1] + red[2][1] + red[3][1];
    float mean = s * (1.f / D_);
    float var = ss * (1.f / D_) - mean * mean;
    float rstd = rsqrtf(var + 1e-5f);
    bf16* xbr = xb + (size_t)bt * D_;
#pragma unroll
    for (int i = 0; i < 3; ++i) {
        int idx = tid + i * 256;
        float o = (v[i] - mean) * rstd * g[idx] + bb[idx];
        xr[idx] = o;
        xbr[idx] = __float2bfloat16(o);
    }
}

// ---------------- CLS writeout ----------------
__global__ void cls_kernel(const float* __restrict__ x, float* __restrict__ out) {
    int o = blockIdx.x * 256 + threadIdx.x;
    if (o >= B_ * D_) return;
    int b = o / D_, d = o % D_;
    out[o] = x[(size_t)(b * T_) * D_ + d];
}

extern "C" void kernel_launch(void* const* d_in, const int* in_sizes, int n_in,
                              void* d_out, int out_size, void* d_ws, size_t ws_size,
                              hipStream_t stream) {
    const int*   batch = (const int*)d_in[0];
    const unsigned char* mask = (const unsigned char*)d_in[1];
    const float* tok  = (const float*)d_in[2];
    const float* pos  = (const float*)d_in[3];
    const float* Wq   = (const float*)d_in[4];
    const float* bq   = (const float*)d_in[5];
    const float* Wk   = (const float*)d_in[6];
    const float* bk   = (const float*)d_in[7];
    const float* Wv   = (const float*)d_in[8];
    const float* bv   = (const float*)d_in[9];
    const float* Wo   = (const float*)d_in[10];
    const float* bo   = (const float*)d_in[11];
    const float* omega= (const float*)d_in[12];
    const float* ln1g = (const float*)d_in[13];
    const float* ln1b = (const float*)d_in[14];
    const float* ln2g = (const float*)d_in[15];
    const float* ln2b = (const float*)d_in[16];
    const float* W1   = (const float*)d_in[17];
    const float* b1   = (const float*)d_in[18];
    const float* W2   = (const float*)d_in[19];
    const float* b2   = (const float*)d_in[20];

    float* out_cls  = (float*)d_out;                   // [B, D]
    float* out_attn = (float*)d_out + B_ * D_;         // [B, H, T, T]

    // workspace layout (~161 MB). qkv [BT,2304] column-slices:
    //   [0,768): q  -> attn-out -> FFN2 out (ln2 res)
    //   [768,1536): k -> Wo-proj out (ln1 res)
    //   [1536,2304): v -> FFN1 mid (GELU)
    char* wsb = (char*)d_ws;
    float* x   = (float*)wsb; wsb += (size_t)BT_ * D_ * 4;        // 49.2 MB
    bf16* xb   = (bf16*)wsb;  wsb += (size_t)BT_ * D_ * 2;        // 24.6 MB
    bf16* qkv  = (bf16*)wsb;  wsb += (size_t)BT_ * QKVN_ * 2;     // 73.7 MB
    bf16* Qf   = (bf16*)wsb;  wsb += (size_t)BT_ * NF_ * 2;       // 12.3 MB
    bf16* Kf   = (bf16*)wsb;  wsb += (size_t)BT_ * NF_ * 2;
    float* KV  = (float*)wsb; wsb += (size_t)B_ * H_ * F_ * DH_ * 4;
    float* Ksum= (float*)wsb; wsb += (size_t)B_ * H_ * F_ * 4;
    float* Z   = (float*)wsb; wsb += (size_t)BT_ * H_ * 4;
    bf16* Wt   = (bf16*)wsb;  wsb += (size_t)6 * D_ * D_ * 2;     // 7.1 MB, reused per layer
    float* qkvb= (float*)wsb; wsb += (size_t)L_ * QKVN_ * 4;      // 110 KB
    int* lengths = (int*)wsb; wsb += 256;

    lengths_kernel<<<1, 256, 0, stream>>>(mask, lengths);
    embed_kernel<<<BT_, 256, 0, stream>>>(batch, tok, pos, x, xb);
    pack_bias<<<(L_ * QKVN_ + 255) / 256, 256, 0, stream>>>(bq, bk, bv, qkvb);

    dim3 qkv_g(QKVN_ / 128, BT_ / 128);   // (18, 125)
    dim3 gemm_g(D_ / 128, BT_ / 128);     // (6, 125)
    dim3 feat_g(BT_ / 128, H_, 2);        // (125, 12, 2)
    dim3 kv_g(H_, B_);                    // (12, 64)
    dim3 tr_g(24, 24, 6);
    dim3 tr_b(32, 8);
    const size_t WS = (size_t)D_ * D_;

    for (int l = 0; l < L_; ++l) {
        transpose_w<<<tr_g, tr_b, 0, stream>>>(Wq, Wk, Wv, Wo, W1, W2, l, Wt);

        // fused QKV: [BT,768] @ [2304,768]^T -> qkv [BT,2304]
        gemm_bt<<<qkv_g, 256, 0, stream>>>(xb, Wt, qkvb + l * QKVN_, qkv,
                                           QKVN_, D_, QKVN_, 0, lengths);

        // features (K=64 per head, fused Q+K dispatch)
        feat_kernel<<<feat_g, 256, 0, stream>>>(qkv, omega + (size_t)l * DH_ * F_,
                                                Qf, Kf, lengths);

        // fused KV + Ksum (MFMA batched per (b,h))
        kvsum_kernel<<<kv_g, 256, 0, stream>>>(Kf, qkv + 2 * D_, QKVN_, KV, Ksum);

        // attn out written into qkv cols [0,768) (q slice dead after Qf)
        attn_out_kernel<<<(BT_ * D_ + 255) / 256, 256, 0, stream>>>(Qf, KV, Ksum, Z, qkv, QKVN_);

        if (l == L_ - 1)
            attnw_kernel<<<dim3(4, B_ * H_), 256, 0, stream>>>(Qf, Kf, Z, out_attn);

        // Wo proj: reads qkv[:,0:768), writes qkv[:,768:1536)
        gemm_bt<<<gemm_g, 256, 0, stream>>>(qkv, Wt + 3 * WS, bo + l * D_, qkv + D_,
                                            D_, QKVN_, QKVN_, 0, lengths);
        ln_kernel<<<BT_, 256, 0, stream>>>(x, qkv + D_, QKVN_, ln1g + l * D_, ln1b + l * D_, xb);

        // FFN1 (GELU): xb @ W1 -> qkv[:,1536:2304)
        gemm_bt<<<gemm_g, 256, 0, stream>>>(xb, Wt + 4 * WS, b1 + l * D_, qkv + 2 * D_,
                                            D_, D_, QKVN_, 1, lengths);
        // FFN2: qkv[:,1536:2304) @ W2 -> qkv[:,0:768)
        gemm_bt<<<gemm_g, 256, 0, stream>>>(qkv + 2 * D_, Wt + 5 * WS, b2 + l * D_, qkv,
                                            D_, QKVN_, QKVN_, 0, lengths);
        ln_kernel<<<BT_, 256, 0, stream>>>(x, qkv, QKVN_, ln2g + l * D_, ln2b + l * D_, xb);
    }

    cls_kernel<<<(B_ * D_ + 255) / 256, 256, 0, stream>>>(x, out_cls);
}

// Round 3
// 3748.594 us; speedup vs baseline: 1.9234x; 1.3038x over previous
//
#include <hip/hip_runtime.h>
#include <hip/hip_bf16.h>

typedef __hip_bfloat16 bf16;
typedef __attribute__((ext_vector_type(4))) float f32x4;
typedef __attribute__((ext_vector_type(8))) short bf16x8;
typedef __attribute__((ext_vector_type(4))) short short4v;

#define B_ 64
#define T_ 250
#define D_ 768
#define H_ 12
#define DH_ 64
#define F_ 32
#define L_ 12
#define BT_ (B_*T_)   // 16000
#define NF_ (H_*F_)   // 384
#define QKVN_ (3*D_)  // 2304
#define KVTN_ 80      // KVt rows: 64 m-cols + 1 Ksum + 15 pad

static __device__ __forceinline__ float b2f(short s) {
    union { float f; unsigned u; } z; z.u = ((unsigned)(unsigned short)s) << 16; return z.f;
}
static __device__ __forceinline__ short f2bs(float f) {
    bf16 b = __float2bfloat16(f);
    return *(short*)&b;
}

// ---------------- lengths (mask dtype autodetect: int32 / float32 / bool8) ----------------
__global__ void lengths_kernel(const unsigned char* __restrict__ mask, int* __restrict__ lengths) {
    __shared__ int not_i32, not_f32;
    const unsigned int* w = (const unsigned int*)mask;
    int tid = threadIdx.x;
    if (tid == 0) { not_i32 = 0; not_f32 = 0; }
    __syncthreads();
    int li = 0, lf = 0;
    for (int i = tid; i < 4000; i += 256) {
        unsigned int v = w[i];
        if (v > 1u) li = 1;
        if (v != 0u && v != 0x3F800000u) lf = 1;
    }
    if (li) not_i32 = 1;
    if (lf) not_f32 = 1;
    __syncthreads();
    int mode = (!not_i32) ? 0 : ((!not_f32) ? 1 : 2);
    if (tid < B_) {
        int cnt = 0;
        if (mode == 0) {
            const int* r = (const int*)mask + tid * T_;
            for (int t = 0; t < T_; ++t) cnt += (r[t] != 0);
        } else if (mode == 1) {
            const unsigned int* r = w + tid * T_;
            for (int t = 0; t < T_; ++t) cnt += (r[t] != 0);
        } else {
            const unsigned char* r = mask + tid * T_;
            for (int t = 0; t < T_; ++t) cnt += (r[t] != 0);
        }
        lengths[tid] = cnt;
    }
}

// ---------------- embedding: x f32 + xb bf16 shadow ----------------
__global__ void embed_kernel(const int* __restrict__ batch, const float* __restrict__ tok,
                             const float* __restrict__ pos, float* __restrict__ x,
                             bf16* __restrict__ xb) {
    int bt = blockIdx.x;
    int t = bt % T_;
    int tok_id = batch[bt];
    const float* tr = tok + (size_t)tok_id * D_;
    const float* pr = pos + (size_t)t * D_;
    float* xr = x + (size_t)bt * D_;
    bf16* xbr = xb + (size_t)bt * D_;
    for (int d = threadIdx.x; d < D_; d += 256) {
        float v = tr[d] + pr[d];
        xr[d] = v;
        xbr[d] = __float2bfloat16(v);
    }
}

// ---------------- per-layer weight transpose+cast: W f32 [K,N] -> Wt bf16 [N,K] ----------------
__global__ __launch_bounds__(256) void transpose_w(
    const float* __restrict__ Wq, const float* __restrict__ Wk, const float* __restrict__ Wv,
    const float* __restrict__ Wo, const float* __restrict__ W1, const float* __restrict__ W2,
    int l, bf16* __restrict__ Wt)
{
    __shared__ float tile[32][33];
    int m = blockIdx.z;
    const float* src;
    switch (m) {
        case 0: src = Wq; break; case 1: src = Wk; break; case 2: src = Wv; break;
        case 3: src = Wo; break; case 4: src = W1; break; default: src = W2; break;
    }
    src += (size_t)l * D_ * D_;
    bf16* dst = Wt + (size_t)m * D_ * D_;
    int k0 = blockIdx.y * 32, n0 = blockIdx.x * 32;
    int tx = threadIdx.x, ty = threadIdx.y;
#pragma unroll
    for (int i = 0; i < 4; ++i)
        tile[ty + i * 8][tx] = src[(size_t)(k0 + ty + i * 8) * D_ + n0 + tx];
    __syncthreads();
#pragma unroll
    for (int i = 0; i < 4; ++i)
        dst[(size_t)(n0 + ty + i * 8) * D_ + k0 + tx] = __float2bfloat16(tile[tx][ty + i * 8]);
}

// ---------------- pack qkv bias: qkvb[l][0..2304) = [bq[l] ; bk[l] ; bv[l]] ----------------
__global__ void pack_bias(const float* __restrict__ bq, const float* __restrict__ bk,
                          const float* __restrict__ bv, float* __restrict__ qkvb) {
    int o = blockIdx.x * 256 + threadIdx.x;
    if (o >= L_ * QKVN_) return;
    int l = o / QKVN_, c = o - l * QKVN_;
    float v;
    if (c < D_) v = bq[l * D_ + c];
    else if (c < 2 * D_) v = bk[l * D_ + c - D_];
    else v = bv[l * D_ + c - 2 * D_];
    qkvb[o] = v;
}

// ---------------- MFMA GEMM: C[16000,N] = A[16000,768] @ Bt[N,768]^T + bias, epilogue acts ----------------
// act: 0 = none, 1 = exact GELU, 2 = relu, 3 = relu + prefix-length mask (rows are bt)
__global__ __launch_bounds__(256) void gemm_bt(
    const bf16* __restrict__ A, const bf16* __restrict__ Bt,
    const float* __restrict__ bias, bf16* __restrict__ C,
    int N, int lda, int ldc, int act, const int* __restrict__ lengths)
{
    const int K = D_;
    __shared__ __attribute__((aligned(16))) short As[128 * 32];
    __shared__ __attribute__((aligned(16))) short Bs[128 * 32];
    const int tid = threadIdx.x;
    const int lane = tid & 63, wave = tid >> 6;
    const int row0 = blockIdx.y * 128, col0 = blockIdx.x * 128;
    const int wm = (wave >> 1) * 64, wn = (wave & 1) * 64;

    f32x4 acc[4][4];
#pragma unroll
    for (int i = 0; i < 4; ++i)
#pragma unroll
        for (int j = 0; j < 4; ++j) acc[i][j] = (f32x4){0.f, 0.f, 0.f, 0.f};

    const int srow = lane >> 2;            // 0..15
    const int scol = (lane & 3) * 8;       // element offset within 32
    const short* Ag = (const short*)A + (size_t)(row0 + srow) * lda + scol;
    const short* Bg = (const short*)Bt + (size_t)(col0 + srow) * K + scol;

    for (int k0 = 0; k0 < K; k0 += 32) {
#pragma unroll
        for (int c = 0; c < 2; ++c) {
            int cc = wave * 2 + c;
            __builtin_amdgcn_global_load_lds(
                (const __attribute__((address_space(1))) unsigned int*)(Ag + (size_t)cc * 16 * lda + k0),
                (__attribute__((address_space(3))) unsigned int*)(As + cc * 512), 16, 0, 0);
            __builtin_amdgcn_global_load_lds(
                (const __attribute__((address_space(1))) unsigned int*)(Bg + (size_t)cc * 16 * K + k0),
                (__attribute__((address_space(3))) unsigned int*)(Bs + cc * 512), 16, 0, 0);
        }
        __syncthreads();
        bf16x8 af[4], bfr[4];
#pragma unroll
        for (int mi = 0; mi < 4; ++mi)
            af[mi] = *(const bf16x8*)(As + ((wm + mi * 16 + (lane & 15)) << 5) + ((lane >> 4) << 3));
#pragma unroll
        for (int ni = 0; ni < 4; ++ni)
            bfr[ni] = *(const bf16x8*)(Bs + ((wn + ni * 16 + (lane & 15)) << 5) + ((lane >> 4) << 3));
#pragma unroll
        for (int mi = 0; mi < 4; ++mi)
#pragma unroll
            for (int ni = 0; ni < 4; ++ni)
                acc[mi][ni] = __builtin_amdgcn_mfma_f32_16x16x32_bf16(af[mi], bfr[ni], acc[mi][ni], 0, 0, 0);
        __syncthreads();
    }

    float bj[4];
#pragma unroll
    for (int ni = 0; ni < 4; ++ni) {
        int col = col0 + wn + ni * 16 + (lane & 15);
        bj[ni] = bias ? bias[col] : 0.f;
    }
#pragma unroll
    for (int mi = 0; mi < 4; ++mi) {
#pragma unroll
        for (int r = 0; r < 4; ++r) {
            int row = row0 + wm + mi * 16 + ((lane >> 4) << 2) + r;
            bool kill = false;
            if (act == 3) { int b = row / T_; int t = row - b * T_; kill = (t >= lengths[b]); }
            size_t base = (size_t)row * ldc + col0 + wn + (lane & 15);
#pragma unroll
            for (int ni = 0; ni < 4; ++ni) {
                float v = acc[mi][ni][r] + bj[ni];
                if (act == 1) v = 0.5f * v * (1.0f + erff(v * 0.70710678118654752f));
                else if (act >= 2) v = fmaxf(v, 0.f);
                if (kill) v = 0.f;
                C[base + ni * 16] = __float2bfloat16(v);
            }
        }
    }
}

// ---------------- features via MFMA, K=64 (block-diag omega): Qf/Kf[bt, h*32+f] ----------------
// grid (BT/128, H, 2); z=0: Qf=relu(q@om), z=1: Kf=relu(k@om) + prefix mask
__global__ __launch_bounds__(256) void feat_kernel(
    const bf16* __restrict__ qkv, const float* __restrict__ om,
    bf16* __restrict__ Qf, bf16* __restrict__ Kf, const int* __restrict__ lengths)
{
    __shared__ __attribute__((aligned(16))) short omT[32 * 64];   // [f][k]
    int z = blockIdx.z, h = blockIdx.y;
    int row0 = blockIdx.x * 128;
    int tid = threadIdx.x, lane = tid & 63, wave = tid >> 6;
    {
        int f = tid >> 3, k0 = (tid & 7) * 8;
#pragma unroll
        for (int j = 0; j < 8; ++j)
            omT[f * 64 + k0 + j] = f2bs(om[(size_t)(k0 + j) * F_ + f]);
    }
    __syncthreads();

    const short* A = (const short*)qkv + (size_t)z * D_ + h * DH_;
    int rsel = lane & 15, kof = (lane >> 4) << 3;

    bf16x8 af[2][2], bfr[2][2];
#pragma unroll
    for (int mi = 0; mi < 2; ++mi) {
        int row = row0 + wave * 32 + mi * 16 + rsel;
#pragma unroll
        for (int ks = 0; ks < 2; ++ks)
            af[mi][ks] = *(const bf16x8*)(A + (size_t)row * QKVN_ + ks * 32 + kof);
    }
#pragma unroll
    for (int ni = 0; ni < 2; ++ni)
#pragma unroll
        for (int ks = 0; ks < 2; ++ks)
            bfr[ni][ks] = *(const bf16x8*)(omT + (ni * 16 + rsel) * 64 + ks * 32 + kof);

    f32x4 acc[2][2];
#pragma unroll
    for (int i = 0; i < 2; ++i)
#pragma unroll
        for (int j = 0; j < 2; ++j) acc[i][j] = (f32x4){0.f, 0.f, 0.f, 0.f};
#pragma unroll
    for (int mi = 0; mi < 2; ++mi)
#pragma unroll
        for (int ni = 0; ni < 2; ++ni)
#pragma unroll
            for (int ks = 0; ks < 2; ++ks)
                acc[mi][ni] = __builtin_amdgcn_mfma_f32_16x16x32_bf16(af[mi][ks], bfr[ni][ks], acc[mi][ni], 0, 0, 0);

    bf16* out = z ? Kf : Qf;
#pragma unroll
    for (int mi = 0; mi < 2; ++mi) {
#pragma unroll
        for (int r = 0; r < 4; ++r) {
            int row = row0 + wave * 32 + mi * 16 + ((lane >> 4) << 2) + r;
            bool kill = false;
            if (z) { int b = row / T_; int t = row - b * T_; kill = (t >= lengths[b]); }
#pragma unroll
            for (int ni = 0; ni < 2; ++ni) {
                float v = fmaxf(acc[mi][ni][r], 0.f);
                if (kill) v = 0.f;
                out[(size_t)row * NF_ + h * F_ + ni * 16 + rsel] = __float2bfloat16(v);
            }
        }
    }
}

// ---------------- fused KV + Ksum via MFMA -> transposed bf16 KVt[b,h][n][f] ----------------
// n<64: KVt[n][f] = sum_s Kf[b,s,h,f]*v[b,s,h,n];  n==64: Ksum;  n=65..79: 0
__global__ __launch_bounds__(256) void kvsum_kernel(
    const bf16* __restrict__ Kf, const bf16* __restrict__ v, int ldv,
    bf16* __restrict__ KVt)
{
    __shared__ short KfS[64][36];    // [s][f]
    __shared__ short vS[64][68];     // [s][m]
    int h = blockIdx.x, b = blockIdx.y;
    int tid = threadIdx.x, lane = tid & 63, wv = tid >> 6;
    int lr = tid >> 2, cp = tid & 3;

    const short* Kg = (const short*)Kf + (size_t)(b * T_) * NF_ + h * F_;
    const short* Vg = (const short*)v + (size_t)(b * T_) * ldv + h * DH_;

    f32x4 acc[2];
    acc[0] = (f32x4){0.f, 0.f, 0.f, 0.f};
    acc[1] = (f32x4){0.f, 0.f, 0.f, 0.f};
    float ksacc = 0.f;

    for (int s0 = 0; s0 < T_; s0 += 64) {
        __syncthreads();
        int s = s0 + lr;
        if (s < T_) {
            bf16x8 k8 = *(const bf16x8*)(Kg + (size_t)s * NF_ + cp * 8);
            *(short4v*)&KfS[lr][cp * 8]     = *((const short4v*)&k8);
            *(short4v*)&KfS[lr][cp * 8 + 4] = *((const short4v*)&k8 + 1);
            bf16x8 v8a = *(const bf16x8*)(Vg + (size_t)s * ldv + cp * 16);
            bf16x8 v8b = *(const bf16x8*)(Vg + (size_t)s * ldv + cp * 16 + 8);
            *(short4v*)&vS[lr][cp * 16]      = *((const short4v*)&v8a);
            *(short4v*)&vS[lr][cp * 16 + 4]  = *((const short4v*)&v8a + 1);
            *(short4v*)&vS[lr][cp * 16 + 8]  = *((const short4v*)&v8b);
            *(short4v*)&vS[lr][cp * 16 + 12] = *((const short4v*)&v8b + 1);
        } else {
            short4v zz = (short4v){0, 0, 0, 0};
            *(short4v*)&KfS[lr][cp * 8]     = zz;
            *(short4v*)&KfS[lr][cp * 8 + 4] = zz;
            *(short4v*)&vS[lr][cp * 16]      = zz;
            *(short4v*)&vS[lr][cp * 16 + 4]  = zz;
            *(short4v*)&vS[lr][cp * 16 + 8]  = zz;
            *(short4v*)&vS[lr][cp * 16 + 12] = zz;
        }
        __syncthreads();
        if (tid < 32) {        // Ksum on wave 0 lanes 0..31 (f = tid)
            float p0 = 0.f, p1 = 0.f;
            for (int ss = 0; ss < 64; ss += 2) {
                p0 += b2f(KfS[ss][tid]);
                p1 += b2f(KfS[ss + 1][tid]);
            }
            ksacc += p0 + p1;
        }
        // transpose-gather fragments: A = Kf^T [f][s], B^T = v^T [m][s]
        bf16x8 af0[2], af1[2], bfr[2];
#pragma unroll
        for (int ks = 0; ks < 2; ++ks) {
            int sb = ks * 32 + ((lane >> 4) << 3);
#pragma unroll
            for (int j = 0; j < 8; ++j) {
                ((short*)&af0[ks])[j] = KfS[sb + j][lane & 15];
                ((short*)&af1[ks])[j] = KfS[sb + j][16 + (lane & 15)];
                ((short*)&bfr[ks])[j] = vS[sb + j][wv * 16 + (lane & 15)];
            }
        }
#pragma unroll
        for (int ks = 0; ks < 2; ++ks) {
            acc[0] = __builtin_amdgcn_mfma_f32_16x16x32_bf16(af0[ks], bfr[ks], acc[0], 0, 0, 0);
            acc[1] = __builtin_amdgcn_mfma_f32_16x16x32_bf16(af1[ks], bfr[ks], acc[1], 0, 0, 0);
        }
    }

    bf16* dst = KVt + (size_t)(b * H_ + h) * KVTN_ * F_;
    int m = wv * 16 + (lane & 15);
#pragma unroll
    for (int mi = 0; mi < 2; ++mi) {
#pragma unroll
        for (int r = 0; r < 4; ++r) {
            int f = mi * 16 + ((lane >> 4) << 2) + r;
            dst[(size_t)m * F_ + f] = __float2bfloat16(acc[mi][r]);
        }
    }
    if (tid < 32) dst[(size_t)64 * F_ + tid] = __float2bfloat16(ksacc);
    if (tid < 240) {            // zero rows 65..79 (15*32 = 480 shorts)
        ((short*)dst)[65 * F_ + tid * 2]     = 0;
        ((short*)dst)[65 * F_ + tid * 2 + 1] = 0;
    }
}

// ---------------- attn out via MFMA: one block per (b,h); 4 waves x 64 t-rows ----------------
// out[t][n] = z * sum_f Qf[t][f]*KVt[n][f], n<64;  zden = column n==64;  Z stored
__global__ __launch_bounds__(256) void attn_mfma(
    const bf16* __restrict__ Qf, const bf16* __restrict__ KVt,
    float* __restrict__ Z, bf16* __restrict__ out, int ldo)
{
    int h = blockIdx.x, b = blockIdx.y;
    int tid = threadIdx.x, lane = tid & 63, wv = tid >> 6;
    int t0 = wv * 64;
    int rsel = lane & 15, kof = (lane >> 4) << 3;

    const short* Qg = (const short*)Qf + h * F_;
    const short* Bg = (const short*)KVt + (size_t)(b * H_ + h) * KVTN_ * F_;

    bf16x8 af[4], bfr[5];
#pragma unroll
    for (int mi = 0; mi < 4; ++mi) {
        int t = t0 + mi * 16 + rsel;
        if (t > T_ - 1) t = T_ - 1;                  // clamp; garbage rows never stored
        af[mi] = *(const bf16x8*)(Qg + (size_t)(b * T_ + t) * NF_ + kof);
    }
#pragma unroll
    for (int ni = 0; ni < 5; ++ni)
        bfr[ni] = *(const bf16x8*)(Bg + (size_t)(ni * 16 + rsel) * F_ + kof);

    f32x4 acc[4][5];
#pragma unroll
    for (int i = 0; i < 4; ++i)
#pragma unroll
        for (int j = 0; j < 5; ++j) acc[i][j] = (f32x4){0.f, 0.f, 0.f, 0.f};
#pragma unroll
    for (int mi = 0; mi < 4; ++mi)
#pragma unroll
        for (int ni = 0; ni < 5; ++ni)
            acc[mi][ni] = __builtin_amdgcn_mfma_f32_16x16x32_bf16(af[mi], bfr[ni], acc[mi][ni], 0, 0, 0);

#pragma unroll
    for (int mi = 0; mi < 4; ++mi) {
#pragma unroll
        for (int r = 0; r < 4; ++r) {
            int t = t0 + mi * 16 + ((lane >> 4) << 2) + r;
            // zden lives in col n=64 -> ni=4, lanes with (lane&15)==0; broadcast to group
            float zden = __shfl(acc[mi][4][r], lane & 48, 64);
            float z = 1.0f / (zden + 1e-6f);
            if (t < T_) {
                if (rsel == 0) Z[(size_t)(b * T_ + t) * H_ + h] = z;
                size_t base = (size_t)(b * T_ + t) * ldo + h * DH_ + rsel;
#pragma unroll
                for (int ni = 0; ni < 4; ++ni)
                    out[base + ni * 16] = __float2bfloat16(acc[mi][ni][r] * z);
            }
        }
    }
}

// ---------------- attn weights via MFMA: w[b,h,t,s] = Z[b,t,h] * sum_f Qf*Kf ----------------
__global__ __launch_bounds__(256) void attnw_kernel(const bf16* __restrict__ Qf,
                                                    const bf16* __restrict__ Kf,
                                                    const float* __restrict__ Z,
                                                    float* __restrict__ out) {
    int tt = blockIdx.x;            // t-tile 0..3
    int bh = blockIdx.y;            // b*H+h
    int b = bh / H_, h = bh - b * H_;
    int tid = threadIdx.x;
    int lane = tid & 63, w = tid >> 6;
    int t0 = tt * 64, s0 = w * 64;
    int kof = (lane >> 4) * 8;

    const short* Qs = (const short*)Qf;
    const short* Ks = (const short*)Kf;

    bf16x8 af[4], bfr[4];
#pragma unroll
    for (int mi = 0; mi < 4; ++mi) {
        int t = t0 + mi * 16 + (lane & 15);
        if (t > T_ - 1) t = T_ - 1;
        af[mi] = *(const bf16x8*)(Qs + ((size_t)(b * T_ + t) * H_ + h) * F_ + kof);
    }
#pragma unroll
    for (int ni = 0; ni < 4; ++ni) {
        int s = s0 + ni * 16 + (lane & 15);
        if (s > T_ - 1) s = T_ - 1;
        bfr[ni] = *(const bf16x8*)(Ks + ((size_t)(b * T_ + s) * H_ + h) * F_ + kof);
    }

    f32x4 acc[4][4];
#pragma unroll
    for (int i = 0; i < 4; ++i)
#pragma unroll
        for (int j = 0; j < 4; ++j) acc[i][j] = (f32x4){0.f, 0.f, 0.f, 0.f};
#pragma unroll
    for (int mi = 0; mi < 4; ++mi)
#pragma unroll
        for (int ni = 0; ni < 4; ++ni)
            acc[mi][ni] = __builtin_amdgcn_mfma_f32_16x16x32_bf16(af[mi], bfr[ni], acc[mi][ni], 0, 0, 0);

#pragma unroll
    for (int mi = 0; mi < 4; ++mi) {
#pragma unroll
        for (int r = 0; r < 4; ++r) {
            int t = t0 + mi * 16 + (lane >> 4) * 4 + r;
            if (t >= T_) continue;
            float z = Z[(size_t)(b * T_ + t) * H_ + h];
            size_t base = ((size_t)bh * T_ + t) * T_;
#pragma unroll
            for (int ni = 0; ni < 4; ++ni) {
                int s = s0 + ni * 16 + (lane & 15);
                if (s < T_) out[base + s] = acc[mi][ni][r] * z;
            }
        }
    }
}

// ---------------- x = LN(x + res); res has row stride ldr; writes f32 x and bf16 xb ----------------
__global__ __launch_bounds__(256) void ln_kernel(float* __restrict__ x, const bf16* __restrict__ res,
                                                 int ldr,
                                                 const float* __restrict__ g, const float* __restrict__ bb,
                                                 bf16* __restrict__ xb) {
    int bt = blockIdx.x, tid = threadIdx.x;
    float* xr = x + (size_t)bt * D_;
    const bf16* rr = res + (size_t)bt * ldr;
    float v[3]; float s = 0.f, ss = 0.f;
#pragma unroll
    for (int i = 0; i < 3; ++i) {
        int idx = tid + i * 256;
        float t = xr[idx] + __bfloat162float(rr[idx]);
        v[i] = t; s += t; ss += t * t;
    }
#pragma unroll
    for (int o = 1; o < 64; o <<= 1) { s += __shfl_xor(s, o, 64); ss += __shfl_xor(ss, o, 64); }
    __shared__ float red[4][2];
    int wave = tid >> 6, lane = tid & 63;
    if (lane == 0) { red[wave][0] = s; red[wave][1] = ss; }
    __syncthreads();
    s = red[0][0] + red[1][0] + red[2][0] + red[3][0];
    ss = red[0][1] + red[1][1] + red[2][1] + red[3][1];
    float mean = s * (1.f / D_);
    float var = ss * (1.f / D_) - mean * mean;
    float rstd = rsqrtf(var + 1e-5f);
    bf16* xbr = xb + (size_t)bt * D_;
#pragma unroll
    for (int i = 0; i < 3; ++i) {
        int idx = tid + i * 256;
        float o = (v[i] - mean) * rstd * g[idx] + bb[idx];
        xr[idx] = o;
        xbr[idx] = __float2bfloat16(o);
    }
}

// ---------------- CLS writeout ----------------
__global__ void cls_kernel(const float* __restrict__ x, float* __restrict__ out) {
    int o = blockIdx.x * 256 + threadIdx.x;
    if (o >= B_ * D_) return;
    int b = o / D_, d = o % D_;
    out[o] = x[(size_t)(b * T_) * D_ + d];
}

extern "C" void kernel_launch(void* const* d_in, const int* in_sizes, int n_in,
                              void* d_out, int out_size, void* d_ws, size_t ws_size,
                              hipStream_t stream) {
    const int*   batch = (const int*)d_in[0];
    const unsigned char* mask = (const unsigned char*)d_in[1];
    const float* tok  = (const float*)d_in[2];
    const float* pos  = (const float*)d_in[3];
    const float* Wq   = (const float*)d_in[4];
    const float* bq   = (const float*)d_in[5];
    const float* Wk   = (const float*)d_in[6];
    const float* bk   = (const float*)d_in[7];
    const float* Wv   = (const float*)d_in[8];
    const float* bv   = (const float*)d_in[9];
    const float* Wo   = (const float*)d_in[10];
    const float* bo   = (const float*)d_in[11];
    const float* omega= (const float*)d_in[12];
    const float* ln1g = (const float*)d_in[13];
    const float* ln1b = (const float*)d_in[14];
    const float* ln2g = (const float*)d_in[15];
    const float* ln2b = (const float*)d_in[16];
    const float* W1   = (const float*)d_in[17];
    const float* b1   = (const float*)d_in[18];
    const float* W2   = (const float*)d_in[19];
    const float* b2   = (const float*)d_in[20];

    float* out_cls  = (float*)d_out;                   // [B, D]
    float* out_attn = (float*)d_out + B_ * D_;         // [B, H, T, T]

    // workspace layout (~160 MB). qkv [BT,2304] column-slices:
    //   [0,768): q  -> attn-out -> FFN2 out (ln2 res)
    //   [768,1536): k -> Wo-proj out (ln1 res)
    //   [1536,2304): v -> FFN1 mid (GELU)
    char* wsb = (char*)d_ws;
    float* x   = (float*)wsb; wsb += (size_t)BT_ * D_ * 4;        // 49.2 MB
    bf16* xb   = (bf16*)wsb;  wsb += (size_t)BT_ * D_ * 2;        // 24.6 MB
    bf16* qkv  = (bf16*)wsb;  wsb += (size_t)BT_ * QKVN_ * 2;     // 73.7 MB
    bf16* Qf   = (bf16*)wsb;  wsb += (size_t)BT_ * NF_ * 2;       // 12.3 MB
    bf16* Kf   = (bf16*)wsb;  wsb += (size_t)BT_ * NF_ * 2;
    bf16* KVt  = (bf16*)wsb;  wsb += (size_t)B_ * H_ * KVTN_ * F_ * 2;  // 3.9 MB
    float* Z   = (float*)wsb; wsb += (size_t)BT_ * H_ * 4;
    bf16* Wt   = (bf16*)wsb;  wsb += (size_t)6 * D_ * D_ * 2;     // 7.1 MB, reused per layer
    float* qkvb= (float*)wsb; wsb += (size_t)L_ * QKVN_ * 4;      // 110 KB
    int* lengths = (int*)wsb; wsb += 256;

    lengths_kernel<<<1, 256, 0, stream>>>(mask, lengths);
    embed_kernel<<<BT_, 256, 0, stream>>>(batch, tok, pos, x, xb);
    pack_bias<<<(L_ * QKVN_ + 255) / 256, 256, 0, stream>>>(bq, bk, bv, qkvb);

    dim3 qkv_g(QKVN_ / 128, BT_ / 128);   // (18, 125)
    dim3 gemm_g(D_ / 128, BT_ / 128);     // (6, 125)
    dim3 feat_g(BT_ / 128, H_, 2);        // (125, 12, 2)
    dim3 kv_g(H_, B_);                    // (12, 64)
    dim3 tr_g(24, 24, 6);
    dim3 tr_b(32, 8);
    const size_t WS = (size_t)D_ * D_;

    for (int l = 0; l < L_; ++l) {
        transpose_w<<<tr_g, tr_b, 0, stream>>>(Wq, Wk, Wv, Wo, W1, W2, l, Wt);

        // fused QKV: [BT,768] @ [2304,768]^T -> qkv [BT,2304]
        gemm_bt<<<qkv_g, 256, 0, stream>>>(xb, Wt, qkvb + l * QKVN_, qkv,
                                           QKVN_, D_, QKVN_, 0, lengths);

        // features (K=64 per head, fused Q+K dispatch)
        feat_kernel<<<feat_g, 256, 0, stream>>>(qkv, omega + (size_t)l * DH_ * F_,
                                                Qf, Kf, lengths);

        // fused KV + Ksum -> transposed bf16 KVt (MFMA batched per (b,h))
        kvsum_kernel<<<kv_g, 256, 0, stream>>>(Kf, qkv + 2 * D_, QKVN_, KVt);

        // attn out via MFMA, written into qkv cols [0,768) (q slice dead after Qf)
        attn_mfma<<<kv_g, 256, 0, stream>>>(Qf, KVt, Z, qkv, QKVN_);

        if (l == L_ - 1)
            attnw_kernel<<<dim3(4, B_ * H_), 256, 0, stream>>>(Qf, Kf, Z, out_attn);

        // Wo proj: reads qkv[:,0:768), writes qkv[:,768:1536)
        gemm_bt<<<gemm_g, 256, 0, stream>>>(qkv, Wt + 3 * WS, bo + l * D_, qkv + D_,
                                            D_, QKVN_, QKVN_, 0, lengths);
        ln_kernel<<<BT_, 256, 0, stream>>>(x, qkv + D_, QKVN_, ln1g + l * D_, ln1b + l * D_, xb);

        // FFN1 (GELU): xb @ W1 -> qkv[:,1536:2304)
        gemm_bt<<<gemm_g, 256, 0, stream>>>(xb, Wt + 4 * WS, b1 + l * D_, qkv + 2 * D_,
                                            D_, D_, QKVN_, 1, lengths);
        // FFN2: qkv[:,1536:2304) @ W2 -> qkv[:,0:768)
        gemm_bt<<<gemm_g, 256, 0, stream>>>(qkv + 2 * D_, Wt + 5 * WS, b2 + l * D_, qkv,
                                            D_, QKVN_, QKVN_, 0, lengths);
        ln_kernel<<<BT_, 256, 0, stream>>>(x, qkv, QKVN_, ln2g + l * D_, ln2b + l * D_, xb);
    }

    cls_kernel<<<(B_ * D_ + 255) / 256, 256, 0, stream>>>(x, out_cls);
}

// Round 4
// 3564.773 us; speedup vs baseline: 2.0226x; 1.0516x over previous
//
#include <hip/hip_runtime.h>
#include <hip/hip_bf16.h>

typedef __hip_bfloat16 bf16;
typedef __attribute__((ext_vector_type(4))) float f32x4;
typedef __attribute__((ext_vector_type(8))) short bf16x8;
typedef __attribute__((ext_vector_type(4))) short short4v;

#define B_ 64
#define T_ 250
#define D_ 768
#define H_ 12
#define DH_ 64
#define F_ 32
#define L_ 12
#define BT_ (B_*T_)   // 16000
#define NF_ (H_*F_)   // 384
#define QKVN_ (3*D_)  // 2304
#define KVTN_ 80      // KVt rows: 64 m-cols + 1 Ksum + 15 pad

static __device__ __forceinline__ float b2f(short s) {
    union { float f; unsigned u; } z; z.u = ((unsigned)(unsigned short)s) << 16; return z.f;
}
static __device__ __forceinline__ short f2bs(float f) {
    bf16 b = __float2bfloat16(f);
    return *(short*)&b;
}

// ---------------- lengths (mask dtype autodetect: int32 / float32 / bool8) ----------------
__global__ void lengths_kernel(const unsigned char* __restrict__ mask, int* __restrict__ lengths) {
    __shared__ int not_i32, not_f32;
    const unsigned int* w = (const unsigned int*)mask;
    int tid = threadIdx.x;
    if (tid == 0) { not_i32 = 0; not_f32 = 0; }
    __syncthreads();
    int li = 0, lf = 0;
    for (int i = tid; i < 4000; i += 256) {
        unsigned int v = w[i];
        if (v > 1u) li = 1;
        if (v != 0u && v != 0x3F800000u) lf = 1;
    }
    if (li) not_i32 = 1;
    if (lf) not_f32 = 1;
    __syncthreads();
    int mode = (!not_i32) ? 0 : ((!not_f32) ? 1 : 2);
    if (tid < B_) {
        int cnt = 0;
        if (mode == 0) {
            const int* r = (const int*)mask + tid * T_;
            for (int t = 0; t < T_; ++t) cnt += (r[t] != 0);
        } else if (mode == 1) {
            const unsigned int* r = w + tid * T_;
            for (int t = 0; t < T_; ++t) cnt += (r[t] != 0);
        } else {
            const unsigned char* r = mask + tid * T_;
            for (int t = 0; t < T_; ++t) cnt += (r[t] != 0);
        }
        lengths[tid] = cnt;
    }
}

// ---------------- embedding: x f32 + xb bf16 shadow ----------------
__global__ void embed_kernel(const int* __restrict__ batch, const float* __restrict__ tok,
                             const float* __restrict__ pos, float* __restrict__ x,
                             bf16* __restrict__ xb) {
    int bt = blockIdx.x;
    int t = bt % T_;
    int tok_id = batch[bt];
    const float* tr = tok + (size_t)tok_id * D_;
    const float* pr = pos + (size_t)t * D_;
    float* xr = x + (size_t)bt * D_;
    bf16* xbr = xb + (size_t)bt * D_;
    for (int d = threadIdx.x; d < D_; d += 256) {
        float v = tr[d] + pr[d];
        xr[d] = v;
        xbr[d] = __float2bfloat16(v);
    }
}

// ---------------- ALL-layer weight transpose+cast: W f32 [K,N] -> Wt bf16 [N,K] ----------------
// grid (24, 24, 72), z = l*6+m
__global__ __launch_bounds__(256) void transpose_w_all(
    const float* __restrict__ Wq, const float* __restrict__ Wk, const float* __restrict__ Wv,
    const float* __restrict__ Wo, const float* __restrict__ W1, const float* __restrict__ W2,
    bf16* __restrict__ Wt)
{
    __shared__ float tile[32][33];
    int zz = blockIdx.z;
    int l = zz / 6, m = zz - l * 6;
    const float* src;
    switch (m) {
        case 0: src = Wq; break; case 1: src = Wk; break; case 2: src = Wv; break;
        case 3: src = Wo; break; case 4: src = W1; break; default: src = W2; break;
    }
    src += (size_t)l * D_ * D_;
    bf16* dst = Wt + (size_t)zz * D_ * D_;
    int k0 = blockIdx.y * 32, n0 = blockIdx.x * 32;
    int tx = threadIdx.x, ty = threadIdx.y;
#pragma unroll
    for (int i = 0; i < 4; ++i)
        tile[ty + i * 8][tx] = src[(size_t)(k0 + ty + i * 8) * D_ + n0 + tx];
    __syncthreads();
#pragma unroll
    for (int i = 0; i < 4; ++i)
        dst[(size_t)(n0 + ty + i * 8) * D_ + k0 + tx] = __float2bfloat16(tile[tx][ty + i * 8]);
}

// ---------------- pack qkv bias: qkvb[l][0..2304) = [bq[l] ; bk[l] ; bv[l]] ----------------
__global__ void pack_bias(const float* __restrict__ bq, const float* __restrict__ bk,
                          const float* __restrict__ bv, float* __restrict__ qkvb) {
    int o = blockIdx.x * 256 + threadIdx.x;
    if (o >= L_ * QKVN_) return;
    int l = o / QKVN_, c = o - l * QKVN_;
    float v;
    if (c < D_) v = bq[l * D_ + c];
    else if (c < 2 * D_) v = bk[l * D_ + c - D_];
    else v = bv[l * D_ + c - 2 * D_];
    qkvb[o] = v;
}

// ---------------- pipelined MFMA GEMM (T2 swizzle + T4 counted vmcnt + T5 setprio) ----------------
// C[16000,N] = A[16000,768] @ Bt[N,768]^T + bias; act: 0 none, 1 GELU, 2 relu, 3 relu+mask
// BM=128, BN=192, BK=64, 8 waves (2x4), 3-slot LDS (120 KB), 3-deep prefetch, K fixed = 768.
#define GP_SLOT 20480          // shorts per slot: A 128*64 + B 192*64
__global__ __launch_bounds__(512, 2) void gemm_pipe(
    const bf16* __restrict__ A, const bf16* __restrict__ Bt,
    const float* __restrict__ bias, bf16* __restrict__ C,
    int N, int lda, int ldc, int act, const int* __restrict__ lengths)
{
    __shared__ __attribute__((aligned(16))) short lds_s[3 * GP_SLOT];
    const int tid = threadIdx.x, lane = tid & 63, wave = tid >> 6;
    const int wm = wave >> 2, wn = wave & 3;
    const int rsel = lane & 15, kq = lane >> 4;

    // bijective XCD swizzle (m204)
    const int gx = gridDim.x;
    const int nwg = gx * gridDim.y;
    int orig = blockIdx.y * gx + blockIdx.x;
    int q = nwg >> 3, r = nwg & 7;
    int xcd = orig & 7, idx = orig >> 3;
    int swz = (xcd < r) ? xcd * (q + 1) + idx : r * (q + 1) + (xcd - r) * q + idx;
    const int row0 = (swz / gx) * 128;
    const int col0 = (swz % gx) * 192;

    // precompute per-lane swizzled global source pointers (k-invariant part)
    const short* gA[2];
    const short* gB[3];
#pragma unroll
    for (int i = 0; i < 2; ++i) {
        int seg = (i * 8 + wave) * 64 + lane;
        int rr = seg >> 3, kb = (seg & 7) ^ (rr & 7);
        gA[i] = (const short*)A + (size_t)(row0 + rr) * lda + kb * 8;
    }
#pragma unroll
    for (int i = 0; i < 3; ++i) {
        int seg = (i * 8 + wave) * 64 + lane;
        int rr = seg >> 3, kb = (seg & 7) ^ (rr & 7);
        gB[i] = (const short*)Bt + (size_t)(col0 + rr) * 768 + kb * 8;
    }

    f32x4 acc[4][3];
#pragma unroll
    for (int i = 0; i < 4; ++i)
#pragma unroll
        for (int j = 0; j < 3; ++j) acc[i][j] = (f32x4){0.f, 0.f, 0.f, 0.f};

    auto STAGE = [&](int kt, int slot) {
        short* base = lds_s + slot * GP_SLOT;
        int kcol = kt * 64;
#pragma unroll
        for (int i = 0; i < 2; ++i) {
            int segb = (i * 8 + wave) * 64;
            __builtin_amdgcn_global_load_lds(
                (const __attribute__((address_space(1))) unsigned int*)(gA[i] + kcol),
                (__attribute__((address_space(3))) unsigned int*)(base + segb * 8), 16, 0, 0);
        }
#pragma unroll
        for (int i = 0; i < 3; ++i) {
            int segb = (i * 8 + wave) * 64;
            __builtin_amdgcn_global_load_lds(
                (const __attribute__((address_space(1))) unsigned int*)(gB[i] + kcol),
                (__attribute__((address_space(3))) unsigned int*)(base + 8192 + segb * 8), 16, 0, 0);
        }
    };

    auto COMPUTE = [&](int slot) {
        const short* sA = lds_s + slot * GP_SLOT;
        const short* sB = sA + 8192;
        bf16x8 bfv[3][2];
#pragma unroll
        for (int n = 0; n < 3; ++n)
#pragma unroll
            for (int ks = 0; ks < 2; ++ks) {
                int rr = wn * 48 + n * 16 + rsel;
                int kb = ks * 4 + kq;
                bfv[n][ks] = *(const bf16x8*)(sB + rr * 64 + ((kb ^ (rr & 7)) << 3));
            }
#pragma unroll
        for (int mp = 0; mp < 2; ++mp) {
            bf16x8 af[2][2];
#pragma unroll
            for (int mi = 0; mi < 2; ++mi)
#pragma unroll
                for (int ks = 0; ks < 2; ++ks) {
                    int rr = wm * 64 + (mp * 2 + mi) * 16 + rsel;
                    int kb = ks * 4 + kq;
                    af[mi][ks] = *(const bf16x8*)(sA + rr * 64 + ((kb ^ (rr & 7)) << 3));
                }
            __builtin_amdgcn_s_setprio(1);
#pragma unroll
            for (int mi = 0; mi < 2; ++mi)
#pragma unroll
                for (int n = 0; n < 3; ++n)
#pragma unroll
                    for (int ks = 0; ks < 2; ++ks)
                        acc[mp * 2 + mi][n] = __builtin_amdgcn_mfma_f32_16x16x32_bf16(
                            af[mi][ks], bfv[n][ks], acc[mp * 2 + mi][n], 0, 0, 0);
            __builtin_amdgcn_s_setprio(0);
        }
    };

    // prologue: 3-deep prefetch (15 loads/wave in flight); wait tile0 (10 = 2 tiles outstanding)
    STAGE(0, 0); STAGE(1, 1); STAGE(2, 2);
    asm volatile("s_waitcnt vmcnt(10)" ::: "memory");
    __builtin_amdgcn_s_barrier();

    int slot = 0;
    for (int kt = 0; kt < 12; ++kt) {
        COMPUTE(slot);
        if (kt < 11) {
            __builtin_amdgcn_s_barrier();              // all waves done reading this slot
            if (kt <= 8) {
                STAGE(kt + 3, slot);                   // refill freed slot
                asm volatile("s_waitcnt vmcnt(10)" ::: "memory");   // wait tile kt+1 landed
            } else if (kt == 9) {
                asm volatile("s_waitcnt vmcnt(5)" ::: "memory");
            } else {
                asm volatile("s_waitcnt vmcnt(0)" ::: "memory");
            }
            __builtin_amdgcn_s_barrier();              // tile kt+1 visible to all
        }
        slot = (slot == 2) ? 0 : slot + 1;
    }

    float bj[3];
#pragma unroll
    for (int n = 0; n < 3; ++n) {
        int col = col0 + wn * 48 + n * 16 + rsel;
        bj[n] = bias ? bias[col] : 0.f;
    }
#pragma unroll
    for (int m = 0; m < 4; ++m) {
#pragma unroll
        for (int rr = 0; rr < 4; ++rr) {
            int row = row0 + wm * 64 + m * 16 + (kq << 2) + rr;
            bool kill = false;
            if (act == 3) { int b = row / T_; int t = row - b * T_; kill = (t >= lengths[b]); }
            size_t base = (size_t)row * ldc + col0 + wn * 48 + rsel;
#pragma unroll
            for (int n = 0; n < 3; ++n) {
                float v = acc[m][n][rr] + bj[n];
                if (act == 1) v = 0.5f * v * (1.0f + erff(v * 0.70710678118654752f));
                else if (act >= 2) v = fmaxf(v, 0.f);
                if (kill) v = 0.f;
                C[base + n * 16] = __float2bfloat16(v);
            }
        }
    }
}

// ---------------- features via MFMA, K=64 (block-diag omega): Qf/Kf[bt, h*32+f] ----------------
// grid (BT/128, H, 2); z=0: Qf=relu(q@om), z=1: Kf=relu(k@om) + prefix mask
__global__ __launch_bounds__(256) void feat_kernel(
    const bf16* __restrict__ qkv, const float* __restrict__ om,
    bf16* __restrict__ Qf, bf16* __restrict__ Kf, const int* __restrict__ lengths)
{
    __shared__ __attribute__((aligned(16))) short omT[32 * 64];   // [f][k]
    int z = blockIdx.z, h = blockIdx.y;
    int row0 = blockIdx.x * 128;
    int tid = threadIdx.x, lane = tid & 63, wave = tid >> 6;
    {
        int f = tid >> 3, k0 = (tid & 7) * 8;
#pragma unroll
        for (int j = 0; j < 8; ++j)
            omT[f * 64 + k0 + j] = f2bs(om[(size_t)(k0 + j) * F_ + f]);
    }
    __syncthreads();

    const short* A = (const short*)qkv + (size_t)z * D_ + h * DH_;
    int rsel = lane & 15, kof = (lane >> 4) << 3;

    bf16x8 af[2][2], bfr[2][2];
#pragma unroll
    for (int mi = 0; mi < 2; ++mi) {
        int row = row0 + wave * 32 + mi * 16 + rsel;
#pragma unroll
        for (int ks = 0; ks < 2; ++ks)
            af[mi][ks] = *(const bf16x8*)(A + (size_t)row * QKVN_ + ks * 32 + kof);
    }
#pragma unroll
    for (int ni = 0; ni < 2; ++ni)
#pragma unroll
        for (int ks = 0; ks < 2; ++ks)
            bfr[ni][ks] = *(const bf16x8*)(omT + (ni * 16 + rsel) * 64 + ks * 32 + kof);

    f32x4 acc[2][2];
#pragma unroll
    for (int i = 0; i < 2; ++i)
#pragma unroll
        for (int j = 0; j < 2; ++j) acc[i][j] = (f32x4){0.f, 0.f, 0.f, 0.f};
#pragma unroll
    for (int mi = 0; mi < 2; ++mi)
#pragma unroll
        for (int ni = 0; ni < 2; ++ni)
#pragma unroll
            for (int ks = 0; ks < 2; ++ks)
                acc[mi][ni] = __builtin_amdgcn_mfma_f32_16x16x32_bf16(af[mi][ks], bfr[ni][ks], acc[mi][ni], 0, 0, 0);

    bf16* out = z ? Kf : Qf;
#pragma unroll
    for (int mi = 0; mi < 2; ++mi) {
#pragma unroll
        for (int r = 0; r < 4; ++r) {
            int row = row0 + wave * 32 + mi * 16 + ((lane >> 4) << 2) + r;
            bool kill = false;
            if (z) { int b = row / T_; int t = row - b * T_; kill = (t >= lengths[b]); }
#pragma unroll
            for (int ni = 0; ni < 2; ++ni) {
                float v = fmaxf(acc[mi][ni][r], 0.f);
                if (kill) v = 0.f;
                out[(size_t)row * NF_ + h * F_ + ni * 16 + rsel] = __float2bfloat16(v);
            }
        }
    }
}

// ---------------- fused KV + Ksum via MFMA -> transposed bf16 KVt[b,h][n][f] ----------------
// n<64: KVt[n][f] = sum_s Kf[b,s,h,f]*v[b,s,h,n];  n==64: Ksum;  n=65..79: 0
__global__ __launch_bounds__(256) void kvsum_kernel(
    const bf16* __restrict__ Kf, const bf16* __restrict__ v, int ldv,
    bf16* __restrict__ KVt)
{
    __shared__ short KfS[64][36];    // [s][f]
    __shared__ short vS[64][68];     // [s][m]
    int h = blockIdx.x, b = blockIdx.y;
    int tid = threadIdx.x, lane = tid & 63, wv = tid >> 6;
    int lr = tid >> 2, cp = tid & 3;

    const short* Kg = (const short*)Kf + (size_t)(b * T_) * NF_ + h * F_;
    const short* Vg = (const short*)v + (size_t)(b * T_) * ldv + h * DH_;

    f32x4 acc[2];
    acc[0] = (f32x4){0.f, 0.f, 0.f, 0.f};
    acc[1] = (f32x4){0.f, 0.f, 0.f, 0.f};
    float ksacc = 0.f;

    for (int s0 = 0; s0 < T_; s0 += 64) {
        __syncthreads();
        int s = s0 + lr;
        if (s < T_) {
            bf16x8 k8 = *(const bf16x8*)(Kg + (size_t)s * NF_ + cp * 8);
            *(short4v*)&KfS[lr][cp * 8]     = *((const short4v*)&k8);
            *(short4v*)&KfS[lr][cp * 8 + 4] = *((const short4v*)&k8 + 1);
            bf16x8 v8a = *(const bf16x8*)(Vg + (size_t)s * ldv + cp * 16);
            bf16x8 v8b = *(const bf16x8*)(Vg + (size_t)s * ldv + cp * 16 + 8);
            *(short4v*)&vS[lr][cp * 16]      = *((const short4v*)&v8a);
            *(short4v*)&vS[lr][cp * 16 + 4]  = *((const short4v*)&v8a + 1);
            *(short4v*)&vS[lr][cp * 16 + 8]  = *((const short4v*)&v8b);
            *(short4v*)&vS[lr][cp * 16 + 12] = *((const short4v*)&v8b + 1);
        } else {
            short4v zz = (short4v){0, 0, 0, 0};
            *(short4v*)&KfS[lr][cp * 8]     = zz;
            *(short4v*)&KfS[lr][cp * 8 + 4] = zz;
            *(short4v*)&vS[lr][cp * 16]      = zz;
            *(short4v*)&vS[lr][cp * 16 + 4]  = zz;
            *(short4v*)&vS[lr][cp * 16 + 8]  = zz;
            *(short4v*)&vS[lr][cp * 16 + 12] = zz;
        }
        __syncthreads();
        if (tid < 32) {        // Ksum on wave 0 lanes 0..31 (f = tid)
            float p0 = 0.f, p1 = 0.f;
            for (int ss = 0; ss < 64; ss += 2) {
                p0 += b2f(KfS[ss][tid]);
                p1 += b2f(KfS[ss + 1][tid]);
            }
            ksacc += p0 + p1;
        }
        // transpose-gather fragments: A = Kf^T [f][s], B^T = v^T [m][s]
        bf16x8 af0[2], af1[2], bfr[2];
#pragma unroll
        for (int ks = 0; ks < 2; ++ks) {
            int sb = ks * 32 + ((lane >> 4) << 3);
#pragma unroll
            for (int j = 0; j < 8; ++j) {
                ((short*)&af0[ks])[j] = KfS[sb + j][lane & 15];
                ((short*)&af1[ks])[j] = KfS[sb + j][16 + (lane & 15)];
                ((short*)&bfr[ks])[j] = vS[sb + j][wv * 16 + (lane & 15)];
            }
        }
#pragma unroll
        for (int ks = 0; ks < 2; ++ks) {
            acc[0] = __builtin_amdgcn_mfma_f32_16x16x32_bf16(af0[ks], bfr[ks], acc[0], 0, 0, 0);
            acc[1] = __builtin_amdgcn_mfma_f32_16x16x32_bf16(af1[ks], bfr[ks], acc[1], 0, 0, 0);
        }
    }

    bf16* dst = KVt + (size_t)(b * H_ + h) * KVTN_ * F_;
    int m = wv * 16 + (lane & 15);
#pragma unroll
    for (int mi = 0; mi < 2; ++mi) {
#pragma unroll
        for (int r = 0; r < 4; ++r) {
            int f = mi * 16 + ((lane >> 4) << 2) + r;
            dst[(size_t)m * F_ + f] = __float2bfloat16(acc[mi][r]);
        }
    }
    if (tid < 32) dst[(size_t)64 * F_ + tid] = __float2bfloat16(ksacc);
    if (tid < 240) {            // zero rows 65..79 (15*32 = 480 shorts)
        ((short*)dst)[65 * F_ + tid * 2]     = 0;
        ((short*)dst)[65 * F_ + tid * 2 + 1] = 0;
    }
}

// ---------------- attn out via MFMA: one block per (b,h); 4 waves x 64 t-rows ----------------
// out[t][n] = z * sum_f Qf[t][f]*KVt[n][f], n<64;  zden = column n==64;  Z stored
__global__ __launch_bounds__(256) void attn_mfma(
    const bf16* __restrict__ Qf, const bf16* __restrict__ KVt,
    float* __restrict__ Z, bf16* __restrict__ out, int ldo)
{
    int h = blockIdx.x, b = blockIdx.y;
    int tid = threadIdx.x, lane = tid & 63, wv = tid >> 6;
    int t0 = wv * 64;
    int rsel = lane & 15, kof = (lane >> 4) << 3;

    const short* Qg = (const short*)Qf + h * F_;
    const short* Bg = (const short*)KVt + (size_t)(b * H_ + h) * KVTN_ * F_;

    bf16x8 af[4], bfr[5];
#pragma unroll
    for (int mi = 0; mi < 4; ++mi) {
        int t = t0 + mi * 16 + rsel;
        if (t > T_ - 1) t = T_ - 1;                  // clamp; garbage rows never stored
        af[mi] = *(const bf16x8*)(Qg + (size_t)(b * T_ + t) * NF_ + kof);
    }
#pragma unroll
    for (int ni = 0; ni < 5; ++ni)
        bfr[ni] = *(const bf16x8*)(Bg + (size_t)(ni * 16 + rsel) * F_ + kof);

    f32x4 acc[4][5];
#pragma unroll
    for (int i = 0; i < 4; ++i)
#pragma unroll
        for (int j = 0; j < 5; ++j) acc[i][j] = (f32x4){0.f, 0.f, 0.f, 0.f};
#pragma unroll
    for (int mi = 0; mi < 4; ++mi)
#pragma unroll
        for (int ni = 0; ni < 5; ++ni)
            acc[mi][ni] = __builtin_amdgcn_mfma_f32_16x16x32_bf16(af[mi], bfr[ni], acc[mi][ni], 0, 0, 0);

#pragma unroll
    for (int mi = 0; mi < 4; ++mi) {
#pragma unroll
        for (int r = 0; r < 4; ++r) {
            int t = t0 + mi * 16 + ((lane >> 4) << 2) + r;
            // zden lives in col n=64 -> ni=4, lanes with (lane&15)==0; broadcast to group
            float zden = __shfl(acc[mi][4][r], lane & 48, 64);
            float z = 1.0f / (zden + 1e-6f);
            if (t < T_) {
                if (rsel == 0) Z[(size_t)(b * T_ + t) * H_ + h] = z;
                size_t base = (size_t)(b * T_ + t) * ldo + h * DH_ + rsel;
#pragma unroll
                for (int ni = 0; ni < 4; ++ni)
                    out[base + ni * 16] = __float2bfloat16(acc[mi][ni][r] * z);
            }
        }
    }
}

// ---------------- attn weights via MFMA: w[b,h,t,s] = Z[b,t,h] * sum_f Qf*Kf ----------------
__global__ __launch_bounds__(256) void attnw_kernel(const bf16* __restrict__ Qf,
                                                    const bf16* __restrict__ Kf,
                                                    const float* __restrict__ Z,
                                                    float* __restrict__ out) {
    int tt = blockIdx.x;            // t-tile 0..3
    int bh = blockIdx.y;            // b*H+h
    int b = bh / H_, h = bh - b * H_;
    int tid = threadIdx.x;
    int lane = tid & 63, w = tid >> 6;
    int t0 = tt * 64, s0 = w * 64;
    int kof = (lane >> 4) * 8;

    const short* Qs = (const short*)Qf;
    const short* Ks = (const short*)Kf;

    bf16x8 af[4], bfr[4];
#pragma unroll
    for (int mi = 0; mi < 4; ++mi) {
        int t = t0 + mi * 16 + (lane & 15);
        if (t > T_ - 1) t = T_ - 1;
        af[mi] = *(const bf16x8*)(Qs + ((size_t)(b * T_ + t) * H_ + h) * F_ + kof);
    }
#pragma unroll
    for (int ni = 0; ni < 4; ++ni) {
        int s = s0 + ni * 16 + (lane & 15);
        if (s > T_ - 1) s = T_ - 1;
        bfr[ni] = *(const bf16x8*)(Ks + ((size_t)(b * T_ + s) * H_ + h) * F_ + kof);
    }

    f32x4 acc[4][4];
#pragma unroll
    for (int i = 0; i < 4; ++i)
#pragma unroll
        for (int j = 0; j < 4; ++j) acc[i][j] = (f32x4){0.f, 0.f, 0.f, 0.f};
#pragma unroll
    for (int mi = 0; mi < 4; ++mi)
#pragma unroll
        for (int ni = 0; ni < 4; ++ni)
            acc[mi][ni] = __builtin_amdgcn_mfma_f32_16x16x32_bf16(af[mi], bfr[ni], acc[mi][ni], 0, 0, 0);

#pragma unroll
    for (int mi = 0; mi < 4; ++mi) {
#pragma unroll
        for (int r = 0; r < 4; ++r) {
            int t = t0 + mi * 16 + (lane >> 4) * 4 + r;
            if (t >= T_) continue;
            float z = Z[(size_t)(b * T_ + t) * H_ + h];
            size_t base = ((size_t)bh * T_ + t) * T_;
#pragma unroll
            for (int ni = 0; ni < 4; ++ni) {
                int s = s0 + ni * 16 + (lane & 15);
                if (s < T_) out[base + s] = acc[mi][ni][r] * z;
            }
        }
    }
}

// ---------------- x = LN(x + res); res has row stride ldr; writes f32 x and bf16 xb ----------------
__global__ __launch_bounds__(256) void ln_kernel(float* __restrict__ x, const bf16* __restrict__ res,
                                                 int ldr,
                                                 const float* __restrict__ g, const float* __restrict__ bb,
                                                 bf16* __restrict__ xb) {
    int bt = blockIdx.x, tid = threadIdx.x;
    float* xr = x + (size_t)bt * D_;
    const bf16* rr = res + (size_t)bt * ldr;
    float v[3]; float s = 0.f, ss = 0.f;
#pragma unroll
    for (int i = 0; i < 3; ++i) {
        int idx = tid + i * 256;
        float t = xr[idx] + __bfloat162float(rr[idx]);
        v[i] = t; s += t; ss += t * t;
    }
#pragma unroll
    for (int o = 1; o < 64; o <<= 1) { s += __shfl_xor(s, o, 64); ss += __shfl_xor(ss, o, 64); }
    __shared__ float red[4][2];
    int wave = tid >> 6, lane = tid & 63;
    if (lane == 0) { red[wave][0] = s; red[wave][1] = ss; }
    __syncthreads();
    s = red[0][0] + red[1][0] + red[2][0] + red[3][0];
    ss = red[0][1] + red[1][1] + red[2][1] + red[3][1];
    float mean = s * (1.f / D_);
    float var = ss * (1.f / D_) - mean * mean;
    float rstd = rsqrtf(var + 1e-5f);
    bf16* xbr = xb + (size_t)bt * D_;
#pragma unroll
    for (int i = 0; i < 3; ++i) {
        int idx = tid + i * 256;
        float o = (v[i] - mean) * rstd * g[idx] + bb[idx];
        xr[idx] = o;
        xbr[idx] = __float2bfloat16(o);
    }
}

// ---------------- CLS writeout ----------------
__global__ void cls_kernel(const float* __restrict__ x, float* __restrict__ out) {
    int o = blockIdx.x * 256 + threadIdx.x;
    if (o >= B_ * D_) return;
    int b = o / D_, d = o % D_;
    out[o] = x[(size_t)(b * T_) * D_ + d];
}

extern "C" void kernel_launch(void* const* d_in, const int* in_sizes, int n_in,
                              void* d_out, int out_size, void* d_ws, size_t ws_size,
                              hipStream_t stream) {
    const int*   batch = (const int*)d_in[0];
    const unsigned char* mask = (const unsigned char*)d_in[1];
    const float* tok  = (const float*)d_in[2];
    const float* pos  = (const float*)d_in[3];
    const float* Wq   = (const float*)d_in[4];
    const float* bq   = (const float*)d_in[5];
    const float* Wk   = (const float*)d_in[6];
    const float* bk   = (const float*)d_in[7];
    const float* Wv   = (const float*)d_in[8];
    const float* bv   = (const float*)d_in[9];
    const float* Wo   = (const float*)d_in[10];
    const float* bo   = (const float*)d_in[11];
    const float* omega= (const float*)d_in[12];
    const float* ln1g = (const float*)d_in[13];
    const float* ln1b = (const float*)d_in[14];
    const float* ln2g = (const float*)d_in[15];
    const float* ln2b = (const float*)d_in[16];
    const float* W1   = (const float*)d_in[17];
    const float* b1   = (const float*)d_in[18];
    const float* W2   = (const float*)d_in[19];
    const float* b2   = (const float*)d_in[20];

    float* out_cls  = (float*)d_out;                   // [B, D]
    float* out_attn = (float*)d_out + B_ * D_;         // [B, H, T, T]

    // workspace layout (~262 MB). qkv [BT,2304] column-slices:
    //   [0,768): q  -> attn-out -> FFN2 out (ln2 res)
    //   [768,1536): k -> Wo-proj out (ln1 res)
    //   [1536,2304): v -> FFN1 mid (GELU)
    char* wsb = (char*)d_ws;
    float* x   = (float*)wsb; wsb += (size_t)BT_ * D_ * 4;        // 49.2 MB
    bf16* xb   = (bf16*)wsb;  wsb += (size_t)BT_ * D_ * 2;        // 24.6 MB
    bf16* qkv  = (bf16*)wsb;  wsb += (size_t)BT_ * QKVN_ * 2;     // 73.7 MB
    bf16* Qf   = (bf16*)wsb;  wsb += (size_t)BT_ * NF_ * 2;       // 12.3 MB
    bf16* Kf   = (bf16*)wsb;  wsb += (size_t)BT_ * NF_ * 2;
    bf16* KVt  = (bf16*)wsb;  wsb += (size_t)B_ * H_ * KVTN_ * F_ * 2;  // 3.9 MB
    float* Z   = (float*)wsb; wsb += (size_t)BT_ * H_ * 4;
    bf16* Wt   = (bf16*)wsb;  wsb += (size_t)L_ * 6 * D_ * D_ * 2;      // 84.9 MB (all layers)
    float* qkvb= (float*)wsb; wsb += (size_t)L_ * QKVN_ * 4;      // 110 KB
    int* lengths = (int*)wsb; wsb += 256;

    lengths_kernel<<<1, 256, 0, stream>>>(mask, lengths);
    embed_kernel<<<BT_, 256, 0, stream>>>(batch, tok, pos, x, xb);
    pack_bias<<<(L_ * QKVN_ + 255) / 256, 256, 0, stream>>>(bq, bk, bv, qkvb);
    transpose_w_all<<<dim3(24, 24, 72), dim3(32, 8), 0, stream>>>(Wq, Wk, Wv, Wo, W1, W2, Wt);

    dim3 qkv_g(QKVN_ / 192, BT_ / 128);   // (12, 125)
    dim3 dxd_g(D_ / 192, BT_ / 128);      // (4, 125)
    dim3 feat_g(BT_ / 128, H_, 2);        // (125, 12, 2)
    dim3 kv_g(H_, B_);                    // (12, 64)
    const size_t WS = (size_t)D_ * D_;

    for (int l = 0; l < L_; ++l) {
        const bf16* Wtl = Wt + (size_t)l * 6 * WS;

        // fused QKV: [BT,768] @ [2304,768]^T -> qkv [BT,2304]
        gemm_pipe<<<qkv_g, 512, 0, stream>>>(xb, Wtl, qkvb + l * QKVN_, qkv,
                                             QKVN_, D_, QKVN_, 0, lengths);

        // features (K=64 per head, fused Q+K dispatch)
        feat_kernel<<<feat_g, 256, 0, stream>>>(qkv, omega + (size_t)l * DH_ * F_,
                                                Qf, Kf, lengths);

        // fused KV + Ksum -> transposed bf16 KVt (MFMA batched per (b,h))
        kvsum_kernel<<<kv_g, 256, 0, stream>>>(Kf, qkv + 2 * D_, QKVN_, KVt);

        // attn out via MFMA, written into qkv cols [0,768) (q slice dead after Qf)
        attn_mfma<<<kv_g, 256, 0, stream>>>(Qf, KVt, Z, qkv, QKVN_);

        if (l == L_ - 1)
            attnw_kernel<<<dim3(4, B_ * H_), 256, 0, stream>>>(Qf, Kf, Z, out_attn);

        // Wo proj: reads qkv[:,0:768), writes qkv[:,768:1536)
        gemm_pipe<<<dxd_g, 512, 0, stream>>>(qkv, Wtl + 3 * WS, bo + l * D_, qkv + D_,
                                             D_, QKVN_, QKVN_, 0, lengths);
        ln_kernel<<<BT_, 256, 0, stream>>>(x, qkv + D_, QKVN_, ln1g + l * D_, ln1b + l * D_, xb);

        // FFN1 (GELU): xb @ W1 -> qkv[:,1536:2304)
        gemm_pipe<<<dxd_g, 512, 0, stream>>>(xb, Wtl + 4 * WS, b1 + l * D_, qkv + 2 * D_,
                                             D_, D_, QKVN_, 1, lengths);
        // FFN2: qkv[:,1536:2304) @ W2 -> qkv[:,0:768)
        gemm_pipe<<<dxd_g, 512, 0, stream>>>(qkv + 2 * D_, Wtl + 5 * WS, b2 + l * D_, qkv,
                                             D_, QKVN_, QKVN_, 0, lengths);
        ln_kernel<<<BT_, 256, 0, stream>>>(x, qkv, QKVN_, ln2g + l * D_, ln2b + l * D_, xb);
    }

    cls_kernel<<<(B_ * D_ + 255) / 256, 256, 0, stream>>>(x, out_cls);
}

// Round 5
// 3352.684 us; speedup vs baseline: 2.1506x; 1.0633x over previous
//
#include <hip/hip_runtime.h>
#include <hip/hip_bf16.h>

typedef __hip_bfloat16 bf16;
typedef __attribute__((ext_vector_type(4))) float f32x4;
typedef __attribute__((ext_vector_type(8))) short bf16x8;
typedef __attribute__((ext_vector_type(4))) short short4v;

#define B_ 64
#define T_ 250
#define D_ 768
#define H_ 12
#define DH_ 64
#define F_ 32
#define L_ 12
#define BT_ (B_*T_)   // 16000
#define BT_P 16128    // padded to 63*256 for BM=256 GEMM tiles
#define NF_ (H_*F_)   // 384
#define QKVN_ (3*D_)  // 2304
#define KVTN_ 80      // KVt rows: 64 m-cols + 1 Ksum + 15 pad

static __device__ __forceinline__ float b2f(short s) {
    union { float f; unsigned u; } z; z.u = ((unsigned)(unsigned short)s) << 16; return z.f;
}
static __device__ __forceinline__ short f2bs(float f) {
    bf16 b = __float2bfloat16(f);
    return *(short*)&b;
}

// ---------------- lengths (mask dtype autodetect: int32 / float32 / bool8) ----------------
__global__ void lengths_kernel(const unsigned char* __restrict__ mask, int* __restrict__ lengths) {
    __shared__ int not_i32, not_f32;
    const unsigned int* w = (const unsigned int*)mask;
    int tid = threadIdx.x;
    if (tid == 0) { not_i32 = 0; not_f32 = 0; }
    __syncthreads();
    int li = 0, lf = 0;
    for (int i = tid; i < 4000; i += 256) {
        unsigned int v = w[i];
        if (v > 1u) li = 1;
        if (v != 0u && v != 0x3F800000u) lf = 1;
    }
    if (li) not_i32 = 1;
    if (lf) not_f32 = 1;
    __syncthreads();
    int mode = (!not_i32) ? 0 : ((!not_f32) ? 1 : 2);
    if (tid < B_) {
        int cnt = 0;
        if (mode == 0) {
            const int* r = (const int*)mask + tid * T_;
            for (int t = 0; t < T_; ++t) cnt += (r[t] != 0);
        } else if (mode == 1) {
            const unsigned int* r = w + tid * T_;
            for (int t = 0; t < T_; ++t) cnt += (r[t] != 0);
        } else {
            const unsigned char* r = mask + tid * T_;
            for (int t = 0; t < T_; ++t) cnt += (r[t] != 0);
        }
        lengths[tid] = cnt;
    }
}

// ---------------- embedding: x f32 + xb bf16 shadow ----------------
__global__ void embed_kernel(const int* __restrict__ batch, const float* __restrict__ tok,
                             const float* __restrict__ pos, float* __restrict__ x,
                             bf16* __restrict__ xb) {
    int bt = blockIdx.x;
    int t = bt % T_;
    int tok_id = batch[bt];
    const float* tr = tok + (size_t)tok_id * D_;
    const float* pr = pos + (size_t)t * D_;
    float* xr = x + (size_t)bt * D_;
    bf16* xbr = xb + (size_t)bt * D_;
    for (int d = threadIdx.x; d < D_; d += 256) {
        float v = tr[d] + pr[d];
        xr[d] = v;
        xbr[d] = __float2bfloat16(v);
    }
}

// ---------------- ALL-layer weight transpose+cast: W f32 [K,N] -> Wt bf16 [N,K] ----------------
// grid (24, 24, 72), z = l*6+m
__global__ __launch_bounds__(256) void transpose_w_all(
    const float* __restrict__ Wq, const float* __restrict__ Wk, const float* __restrict__ Wv,
    const float* __restrict__ Wo, const float* __restrict__ W1, const float* __restrict__ W2,
    bf16* __restrict__ Wt)
{
    __shared__ float tile[32][33];
    int zz = blockIdx.z;
    int l = zz / 6, m = zz - l * 6;
    const float* src;
    switch (m) {
        case 0: src = Wq; break; case 1: src = Wk; break; case 2: src = Wv; break;
        case 3: src = Wo; break; case 4: src = W1; break; default: src = W2; break;
    }
    src += (size_t)l * D_ * D_;
    bf16* dst = Wt + (size_t)zz * D_ * D_;
    int k0 = blockIdx.y * 32, n0 = blockIdx.x * 32;
    int tx = threadIdx.x, ty = threadIdx.y;
#pragma unroll
    for (int i = 0; i < 4; ++i)
        tile[ty + i * 8][tx] = src[(size_t)(k0 + ty + i * 8) * D_ + n0 + tx];
    __syncthreads();
#pragma unroll
    for (int i = 0; i < 4; ++i)
        dst[(size_t)(n0 + ty + i * 8) * D_ + k0 + tx] = __float2bfloat16(tile[tx][ty + i * 8]);
}

// ---------------- pack qkv bias: qkvb[l][0..2304) = [bq[l] ; bk[l] ; bv[l]] ----------------
__global__ void pack_bias(const float* __restrict__ bq, const float* __restrict__ bk,
                          const float* __restrict__ bv, float* __restrict__ qkvb) {
    int o = blockIdx.x * 256 + threadIdx.x;
    if (o >= L_ * QKVN_) return;
    int l = o / QKVN_, c = o - l * QKVN_;
    float v;
    if (c < D_) v = bq[l * D_ + c];
    else if (c < 2 * D_) v = bk[l * D_ + c - D_];
    else v = bv[l * D_ + c - 2 * D_];
    qkvb[o] = v;
}

// ---------------- pipelined MFMA GEMM, BM=256 BN=192 BK=64, wave tile 128x48 ----------------
// C[16128,N] = A[16128,768] @ Bt[N,768]^T + bias; act: 0 none, 1 GELU, 2 relu, 3 relu+mask
// 8 waves (2Mx4N), 2-slot LDS (114.7 KB), depth-1 prefetch, counted vmcnt, T2 XOR swizzle.
// Arithmetic intensity: 458 B(LDS)/MFMA < 515 crossover -> MFMA-bound (R3 was 583 -> LDS-bound).
#define GP_SLOT 28672          // shorts per slot: A 256*64 + B 192*64
__global__ __launch_bounds__(512, 2) void gemm_pipe(
    const bf16* __restrict__ A, const bf16* __restrict__ Bt,
    const float* __restrict__ bias, bf16* __restrict__ C,
    int N, int lda, int ldc, int act, const int* __restrict__ lengths)
{
    __shared__ __attribute__((aligned(16))) short lds_s[2 * GP_SLOT];
    const int tid = threadIdx.x, lane = tid & 63, wave = tid >> 6;
    const int wm = wave >> 2, wn = wave & 3;
    const int rsel = lane & 15, kq = lane >> 4;

    // bijective XCD swizzle (m204)
    const int gx = gridDim.x;
    const int nwg = gx * gridDim.y;
    int orig = blockIdx.y * gx + blockIdx.x;
    int q = nwg >> 3, r = nwg & 7;
    int xcd = orig & 7, idx = orig >> 3;
    int swz = (xcd < r) ? xcd * (q + 1) + idx : r * (q + 1) + (xcd - r) * q + idx;
    const int row0 = (swz / gx) * 256;
    const int col0 = (swz % gx) * 192;

    // per-lane staging bases. Round j stages 64 LDS rows; lane covers row (wave*8 + lane/8),
    // col-block (lane&7). Swizzle: LDS[row][b] = G[row][b ^ (row&7)], row&7 == (lane>>3)&7.
    const int srow = wave * 8 + (lane >> 3);
    const int sblk = (lane & 7) ^ ((lane >> 3) & 7);
    const short* gA = (const short*)A + (size_t)(row0 + srow) * lda + sblk * 8;
    const short* gB = (const short*)Bt + (size_t)(col0 + srow) * 768 + sblk * 8;
    const int ldest = wave * 512;          // shorts; + j*4096

    f32x4 acc[8][3];
#pragma unroll
    for (int i = 0; i < 8; ++i)
#pragma unroll
        for (int j = 0; j < 3; ++j) acc[i][j] = (f32x4){0.f, 0.f, 0.f, 0.f};

    auto STAGE = [&](int kt, int slot) {
        short* base = lds_s + slot * GP_SLOT;
        int kc = kt * 64;
#pragma unroll
        for (int j = 0; j < 4; ++j)
            __builtin_amdgcn_global_load_lds(
                (const __attribute__((address_space(1))) unsigned int*)(gA + (size_t)(j * 64) * lda + kc),
                (__attribute__((address_space(3))) unsigned int*)(base + j * 4096 + ldest), 16, 0, 0);
#pragma unroll
        for (int j = 0; j < 3; ++j)
            __builtin_amdgcn_global_load_lds(
                (const __attribute__((address_space(1))) unsigned int*)(gB + (size_t)(j * 64) * 768 + kc),
                (__attribute__((address_space(3))) unsigned int*)(base + 16384 + j * 4096 + ldest), 16, 0, 0);
    };

    auto COMPUTE = [&](int slot) {
        const short* sA = lds_s + slot * GP_SLOT;
        const short* sB = sA + 16384;
#pragma unroll
        for (int ks = 0; ks < 2; ++ks) {
            int kb = ks * 4 + kq;
            bf16x8 bv[3];
#pragma unroll
            for (int n = 0; n < 3; ++n) {
                int rowb = wn * 48 + n * 16 + rsel;
                bv[n] = *(const bf16x8*)(sB + rowb * 64 + ((kb ^ (rowb & 7)) << 3));
            }
#pragma unroll
            for (int mh = 0; mh < 2; ++mh) {
                bf16x8 av[4];
#pragma unroll
                for (int m2 = 0; m2 < 4; ++m2) {
                    int rowa = wm * 128 + (mh * 4 + m2) * 16 + rsel;
                    av[m2] = *(const bf16x8*)(sA + rowa * 64 + ((kb ^ (rowa & 7)) << 3));
                }
                __builtin_amdgcn_s_setprio(1);
#pragma unroll
                for (int m2 = 0; m2 < 4; ++m2)
#pragma unroll
                    for (int n = 0; n < 3; ++n)
                        acc[mh * 4 + m2][n] = __builtin_amdgcn_mfma_f32_16x16x32_bf16(
                            av[m2], bv[n], acc[mh * 4 + m2][n], 0, 0, 0);
                __builtin_amdgcn_s_setprio(0);
            }
        }
    };

    // prologue: depth-1 prefetch (7 loads/wave per tile; 14 in flight); wait tile 0
    STAGE(0, 0); STAGE(1, 1);
    asm volatile("s_waitcnt vmcnt(7)" ::: "memory");
    __builtin_amdgcn_s_barrier();

    for (int t = 0; t < 12; ++t) {
        COMPUTE(t & 1);
        if (t < 11) {
            __builtin_amdgcn_s_barrier();          // all waves done reading slot t&1
            if (t < 10) {
                STAGE(t + 2, t & 1);               // refill freed slot
                asm volatile("s_waitcnt vmcnt(7)" ::: "memory");   // tile t+1 landed
            } else {
                asm volatile("s_waitcnt vmcnt(0)" ::: "memory");
            }
            __builtin_amdgcn_s_barrier();          // tile t+1 visible to all
        }
    }

    float bj[3];
#pragma unroll
    for (int n = 0; n < 3; ++n) {
        int col = col0 + wn * 48 + n * 16 + rsel;
        bj[n] = bias ? bias[col] : 0.f;
    }
#pragma unroll
    for (int mi = 0; mi < 8; ++mi) {
#pragma unroll
        for (int rr = 0; rr < 4; ++rr) {
            int row = row0 + wm * 128 + mi * 16 + (kq << 2) + rr;
            bool kill = false;
            if (act == 3) { int b = row / T_; int t = row - b * T_; kill = (t >= lengths[b & 63]); }
            size_t base = (size_t)row * ldc + col0 + wn * 48 + rsel;
#pragma unroll
            for (int n = 0; n < 3; ++n) {
                float v = acc[mi][n][rr] + bj[n];
                if (act == 1) v = 0.5f * v * (1.0f + erff(v * 0.70710678118654752f));
                else if (act >= 2) v = fmaxf(v, 0.f);
                if (kill) v = 0.f;
                C[base + n * 16] = __float2bfloat16(v);
            }
        }
    }
}

// ---------------- features via MFMA, K=64 (block-diag omega): Qf/Kf[bt, h*32+f] ----------------
// grid (BT/128, H, 2); z=0: Qf=relu(q@om), z=1: Kf=relu(k@om) + prefix mask
__global__ __launch_bounds__(256) void feat_kernel(
    const bf16* __restrict__ qkv, const float* __restrict__ om,
    bf16* __restrict__ Qf, bf16* __restrict__ Kf, const int* __restrict__ lengths)
{
    __shared__ __attribute__((aligned(16))) short omT[32 * 64];   // [f][k]
    int z = blockIdx.z, h = blockIdx.y;
    int row0 = blockIdx.x * 128;
    int tid = threadIdx.x, lane = tid & 63, wave = tid >> 6;
    {
        int f = tid >> 3, k0 = (tid & 7) * 8;
#pragma unroll
        for (int j = 0; j < 8; ++j)
            omT[f * 64 + k0 + j] = f2bs(om[(size_t)(k0 + j) * F_ + f]);
    }
    __syncthreads();

    const short* A = (const short*)qkv + (size_t)z * D_ + h * DH_;
    int rsel = lane & 15, kof = (lane >> 4) << 3;

    bf16x8 af[2][2], bfr[2][2];
#pragma unroll
    for (int mi = 0; mi < 2; ++mi) {
        int row = row0 + wave * 32 + mi * 16 + rsel;
#pragma unroll
        for (int ks = 0; ks < 2; ++ks)
            af[mi][ks] = *(const bf16x8*)(A + (size_t)row * QKVN_ + ks * 32 + kof);
    }
#pragma unroll
    for (int ni = 0; ni < 2; ++ni)
#pragma unroll
        for (int ks = 0; ks < 2; ++ks)
            bfr[ni][ks] = *(const bf16x8*)(omT + (ni * 16 + rsel) * 64 + ks * 32 + kof);

    f32x4 acc[2][2];
#pragma unroll
    for (int i = 0; i < 2; ++i)
#pragma unroll
        for (int j = 0; j < 2; ++j) acc[i][j] = (f32x4){0.f, 0.f, 0.f, 0.f};
#pragma unroll
    for (int mi = 0; mi < 2; ++mi)
#pragma unroll
        for (int ni = 0; ni < 2; ++ni)
#pragma unroll
            for (int ks = 0; ks < 2; ++ks)
                acc[mi][ni] = __builtin_amdgcn_mfma_f32_16x16x32_bf16(af[mi][ks], bfr[ni][ks], acc[mi][ni], 0, 0, 0);

    bf16* out = z ? Kf : Qf;
#pragma unroll
    for (int mi = 0; mi < 2; ++mi) {
#pragma unroll
        for (int r = 0; r < 4; ++r) {
            int row = row0 + wave * 32 + mi * 16 + ((lane >> 4) << 2) + r;
            bool kill = false;
            if (z) { int b = row / T_; int t = row - b * T_; kill = (t >= lengths[b]); }
#pragma unroll
            for (int ni = 0; ni < 2; ++ni) {
                float v = fmaxf(acc[mi][ni][r], 0.f);
                if (kill) v = 0.f;
                out[(size_t)row * NF_ + h * F_ + ni * 16 + rsel] = __float2bfloat16(v);
            }
        }
    }
}

// ---------------- fused KV + Ksum via MFMA -> transposed bf16 KVt[b,h][n][f] ----------------
// n<64: KVt[n][f] = sum_s Kf[b,s,h,f]*v[b,s,h,n];  n==64: Ksum;  n=65..79: 0
__global__ __launch_bounds__(256) void kvsum_kernel(
    const bf16* __restrict__ Kf, const bf16* __restrict__ v, int ldv,
    bf16* __restrict__ KVt)
{
    __shared__ short KfS[64][36];    // [s][f]
    __shared__ short vS[64][68];     // [s][m]
    int h = blockIdx.x, b = blockIdx.y;
    int tid = threadIdx.x, lane = tid & 63, wv = tid >> 6;
    int lr = tid >> 2, cp = tid & 3;

    const short* Kg = (const short*)Kf + (size_t)(b * T_) * NF_ + h * F_;
    const short* Vg = (const short*)v + (size_t)(b * T_) * ldv + h * DH_;

    f32x4 acc[2];
    acc[0] = (f32x4){0.f, 0.f, 0.f, 0.f};
    acc[1] = (f32x4){0.f, 0.f, 0.f, 0.f};
    float ksacc = 0.f;

    for (int s0 = 0; s0 < T_; s0 += 64) {
        __syncthreads();
        int s = s0 + lr;
        if (s < T_) {
            bf16x8 k8 = *(const bf16x8*)(Kg + (size_t)s * NF_ + cp * 8);
            *(short4v*)&KfS[lr][cp * 8]     = *((const short4v*)&k8);
            *(short4v*)&KfS[lr][cp * 8 + 4] = *((const short4v*)&k8 + 1);
            bf16x8 v8a = *(const bf16x8*)(Vg + (size_t)s * ldv + cp * 16);
            bf16x8 v8b = *(const bf16x8*)(Vg + (size_t)s * ldv + cp * 16 + 8);
            *(short4v*)&vS[lr][cp * 16]      = *((const short4v*)&v8a);
            *(short4v*)&vS[lr][cp * 16 + 4]  = *((const short4v*)&v8a + 1);
            *(short4v*)&vS[lr][cp * 16 + 8]  = *((const short4v*)&v8b);
            *(short4v*)&vS[lr][cp * 16 + 12] = *((const short4v*)&v8b + 1);
        } else {
            short4v zz = (short4v){0, 0, 0, 0};
            *(short4v*)&KfS[lr][cp * 8]     = zz;
            *(short4v*)&KfS[lr][cp * 8 + 4] = zz;
            *(short4v*)&vS[lr][cp * 16]      = zz;
            *(short4v*)&vS[lr][cp * 16 + 4]  = zz;
            *(short4v*)&vS[lr][cp * 16 + 8]  = zz;
            *(short4v*)&vS[lr][cp * 16 + 12] = zz;
        }
        __syncthreads();
        if (tid < 32) {        // Ksum on wave 0 lanes 0..31 (f = tid)
            float p0 = 0.f, p1 = 0.f;
            for (int ss = 0; ss < 64; ss += 2) {
                p0 += b2f(KfS[ss][tid]);
                p1 += b2f(KfS[ss + 1][tid]);
            }
            ksacc += p0 + p1;
        }
        // transpose-gather fragments: A = Kf^T [f][s], B^T = v^T [m][s]
        bf16x8 af0[2], af1[2], bfr[2];
#pragma unroll
        for (int ks = 0; ks < 2; ++ks) {
            int sb = ks * 32 + ((lane >> 4) << 3);
#pragma unroll
            for (int j = 0; j < 8; ++j) {
                ((short*)&af0[ks])[j] = KfS[sb + j][lane & 15];
                ((short*)&af1[ks])[j] = KfS[sb + j][16 + (lane & 15)];
                ((short*)&bfr[ks])[j] = vS[sb + j][wv * 16 + (lane & 15)];
            }
        }
#pragma unroll
        for (int ks = 0; ks < 2; ++ks) {
            acc[0] = __builtin_amdgcn_mfma_f32_16x16x32_bf16(af0[ks], bfr[ks], acc[0], 0, 0, 0);
            acc[1] = __builtin_amdgcn_mfma_f32_16x16x32_bf16(af1[ks], bfr[ks], acc[1], 0, 0, 0);
        }
    }

    bf16* dst = KVt + (size_t)(b * H_ + h) * KVTN_ * F_;
    int m = wv * 16 + (lane & 15);
#pragma unroll
    for (int mi = 0; mi < 2; ++mi) {
#pragma unroll
        for (int r = 0; r < 4; ++r) {
            int f = mi * 16 + ((lane >> 4) << 2) + r;
            dst[(size_t)m * F_ + f] = __float2bfloat16(acc[mi][r]);
        }
    }
    if (tid < 32) dst[(size_t)64 * F_ + tid] = __float2bfloat16(ksacc);
    if (tid < 240) {            // zero rows 65..79 (15*32 = 480 shorts)
        ((short*)dst)[65 * F_ + tid * 2]     = 0;
        ((short*)dst)[65 * F_ + tid * 2 + 1] = 0;
    }
}

// ---------------- attn out via MFMA: one block per (b,h); 4 waves x 64 t-rows ----------------
// out[t][n] = z * sum_f Qf[t][f]*KVt[n][f], n<64;  zden = column n==64;  Z stored
__global__ __launch_bounds__(256) void attn_mfma(
    const bf16* __restrict__ Qf, const bf16* __restrict__ KVt,
    float* __restrict__ Z, bf16* __restrict__ out, int ldo)
{
    int h = blockIdx.x, b = blockIdx.y;
    int tid = threadIdx.x, lane = tid & 63, wv = tid >> 6;
    int t0 = wv * 64;
    int rsel = lane & 15, kof = (lane >> 4) << 3;

    const short* Qg = (const short*)Qf + h * F_;
    const short* Bg = (const short*)KVt + (size_t)(b * H_ + h) * KVTN_ * F_;

    bf16x8 af[4], bfr[5];
#pragma unroll
    for (int mi = 0; mi < 4; ++mi) {
        int t = t0 + mi * 16 + rsel;
        if (t > T_ - 1) t = T_ - 1;                  // clamp; garbage rows never stored
        af[mi] = *(const bf16x8*)(Qg + (size_t)(b * T_ + t) * NF_ + kof);
    }
#pragma unroll
    for (int ni = 0; ni < 5; ++ni)
        bfr[ni] = *(const bf16x8*)(Bg + (size_t)(ni * 16 + rsel) * F_ + kof);

    f32x4 acc[4][5];
#pragma unroll
    for (int i = 0; i < 4; ++i)
#pragma unroll
        for (int j = 0; j < 5; ++j) acc[i][j] = (f32x4){0.f, 0.f, 0.f, 0.f};
#pragma unroll
    for (int mi = 0; mi < 4; ++mi)
#pragma unroll
        for (int ni = 0; ni < 5; ++ni)
            acc[mi][ni] = __builtin_amdgcn_mfma_f32_16x16x32_bf16(af[mi], bfr[ni], acc[mi][ni], 0, 0, 0);

#pragma unroll
    for (int mi = 0; mi < 4; ++mi) {
#pragma unroll
        for (int r = 0; r < 4; ++r) {
            int t = t0 + mi * 16 + ((lane >> 4) << 2) + r;
            // zden lives in col n=64 -> ni=4, lanes with (lane&15)==0; broadcast to group
            float zden = __shfl(acc[mi][4][r], lane & 48, 64);
            float z = 1.0f / (zden + 1e-6f);
            if (t < T_) {
                if (rsel == 0) Z[(size_t)(b * T_ + t) * H_ + h] = z;
                size_t base = (size_t)(b * T_ + t) * ldo + h * DH_ + rsel;
#pragma unroll
                for (int ni = 0; ni < 4; ++ni)
                    out[base + ni * 16] = __float2bfloat16(acc[mi][ni][r] * z);
            }
        }
    }
}

// ---------------- attn weights via MFMA: w[b,h,t,s] = Z[b,t,h] * sum_f Qf*Kf ----------------
__global__ __launch_bounds__(256) void attnw_kernel(const bf16* __restrict__ Qf,
                                                    const bf16* __restrict__ Kf,
                                                    const float* __restrict__ Z,
                                                    float* __restrict__ out) {
    int tt = blockIdx.x;            // t-tile 0..3
    int bh = blockIdx.y;            // b*H+h
    int b = bh / H_, h = bh - b * H_;
    int tid = threadIdx.x;
    int lane = tid & 63, w = tid >> 6;
    int t0 = tt * 64, s0 = w * 64;
    int kof = (lane >> 4) * 8;

    const short* Qs = (const short*)Qf;
    const short* Ks = (const short*)Kf;

    bf16x8 af[4], bfr[4];
#pragma unroll
    for (int mi = 0; mi < 4; ++mi) {
        int t = t0 + mi * 16 + (lane & 15);
        if (t > T_ - 1) t = T_ - 1;
        af[mi] = *(const bf16x8*)(Qs + ((size_t)(b * T_ + t) * H_ + h) * F_ + kof);
    }
#pragma unroll
    for (int ni = 0; ni < 4; ++ni) {
        int s = s0 + ni * 16 + (lane & 15);
        if (s > T_ - 1) s = T_ - 1;
        bfr[ni] = *(const bf16x8*)(Ks + ((size_t)(b * T_ + s) * H_ + h) * F_ + kof);
    }

    f32x4 acc[4][4];
#pragma unroll
    for (int i = 0; i < 4; ++i)
#pragma unroll
        for (int j = 0; j < 4; ++j) acc[i][j] = (f32x4){0.f, 0.f, 0.f, 0.f};
#pragma unroll
    for (int mi = 0; mi < 4; ++mi)
#pragma unroll
        for (int ni = 0; ni < 4; ++ni)
            acc[mi][ni] = __builtin_amdgcn_mfma_f32_16x16x32_bf16(af[mi], bfr[ni], acc[mi][ni], 0, 0, 0);

#pragma unroll
    for (int mi = 0; mi < 4; ++mi) {
#pragma unroll
        for (int r = 0; r < 4; ++r) {
            int t = t0 + mi * 16 + (lane >> 4) * 4 + r;
            if (t >= T_) continue;
            float z = Z[(size_t)(b * T_ + t) * H_ + h];
            size_t base = ((size_t)bh * T_ + t) * T_;
#pragma unroll
            for (int ni = 0; ni < 4; ++ni) {
                int s = s0 + ni * 16 + (lane & 15);
                if (s < T_) out[base + s] = acc[mi][ni][r] * z;
            }
        }
    }
}

// ---------------- x = LN(x + res); res has row stride ldr; writes f32 x and bf16 xb ----------------
__global__ __launch_bounds__(256) void ln_kernel(float* __restrict__ x, const bf16* __restrict__ res,
                                                 int ldr,
                                                 const float* __restrict__ g, const float* __restrict__ bb,
                                                 bf16* __restrict__ xb) {
    int bt = blockIdx.x, tid = threadIdx.x;
    float* xr = x + (size_t)bt * D_;
    const bf16* rr = res + (size_t)bt * ldr;
    float v[3]; float s = 0.f, ss = 0.f;
#pragma unroll
    for (int i = 0; i < 3; ++i) {
        int idx = tid + i * 256;
        float t = xr[idx] + __bfloat162float(rr[idx]);
        v[i] = t; s += t; ss += t * t;
    }
#pragma unroll
    for (int o = 1; o < 64; o <<= 1) { s += __shfl_xor(s, o, 64); ss += __shfl_xor(ss, o, 64); }
    __shared__ float red[4][2];
    int wave = tid >> 6, lane = tid & 63;
    if (lane == 0) { red[wave][0] = s; red[wave][1] = ss; }
    __syncthreads();
    s = red[0][0] + red[1][0] + red[2][0] + red[3][0];
    ss = red[0][1] + red[1][1] + red[2][1] + red[3][1];
    float mean = s * (1.f / D_);
    float var = ss * (1.f / D_) - mean * mean;
    float rstd = rsqrtf(var + 1e-5f);
    bf16* xbr = xb + (size_t)bt * D_;
#pragma unroll
    for (int i = 0; i < 3; ++i) {
        int idx = tid + i * 256;
        float o = (v[i] - mean) * rstd * g[idx] + bb[idx];
        xr[idx] = o;
        xbr[idx] = __float2bfloat16(o);
    }
}

// ---------------- CLS writeout ----------------
__global__ void cls_kernel(const float* __restrict__ x, float* __restrict__ out) {
    int o = blockIdx.x * 256 + threadIdx.x;
    if (o >= B_ * D_) return;
    int b = o / D_, d = o % D_;
    out[o] = x[(size_t)(b * T_) * D_ + d];
}

extern "C" void kernel_launch(void* const* d_in, const int* in_sizes, int n_in,
                              void* d_out, int out_size, void* d_ws, size_t ws_size,
                              hipStream_t stream) {
    const int*   batch = (const int*)d_in[0];
    const unsigned char* mask = (const unsigned char*)d_in[1];
    const float* tok  = (const float*)d_in[2];
    const float* pos  = (const float*)d_in[3];
    const float* Wq   = (const float*)d_in[4];
    const float* bq   = (const float*)d_in[5];
    const float* Wk   = (const float*)d_in[6];
    const float* bk   = (const float*)d_in[7];
    const float* Wv   = (const float*)d_in[8];
    const float* bv   = (const float*)d_in[9];
    const float* Wo   = (const float*)d_in[10];
    const float* bo   = (const float*)d_in[11];
    const float* omega= (const float*)d_in[12];
    const float* ln1g = (const float*)d_in[13];
    const float* ln1b = (const float*)d_in[14];
    const float* ln2g = (const float*)d_in[15];
    const float* ln2b = (const float*)d_in[16];
    const float* W1   = (const float*)d_in[17];
    const float* b1   = (const float*)d_in[18];
    const float* W2   = (const float*)d_in[19];
    const float* b2   = (const float*)d_in[20];

    float* out_cls  = (float*)d_out;                   // [B, D]
    float* out_attn = (float*)d_out + B_ * D_;         // [B, H, T, T]

    // workspace layout (~263 MB). xb/qkv padded to BT_P=16128 rows for BM=256 tiles;
    // pad rows hold garbage and are only ever read as A-rows of pad output rows.
    // qkv [BT_P,2304] column-slices:
    //   [0,768): q  -> attn-out -> FFN2 out (ln2 res)
    //   [768,1536): k -> Wo-proj out (ln1 res)
    //   [1536,2304): v -> FFN1 mid (GELU)
    char* wsb = (char*)d_ws;
    float* x   = (float*)wsb; wsb += (size_t)BT_ * D_ * 4;        // 49.2 MB
    bf16* xb   = (bf16*)wsb;  wsb += (size_t)BT_P * D_ * 2;       // 24.8 MB
    bf16* qkv  = (bf16*)wsb;  wsb += (size_t)BT_P * QKVN_ * 2;    // 74.3 MB
    bf16* Qf   = (bf16*)wsb;  wsb += (size_t)BT_ * NF_ * 2;       // 12.3 MB
    bf16* Kf   = (bf16*)wsb;  wsb += (size_t)BT_ * NF_ * 2;
    bf16* KVt  = (bf16*)wsb;  wsb += (size_t)B_ * H_ * KVTN_ * F_ * 2;  // 3.9 MB
    float* Z   = (float*)wsb; wsb += (size_t)BT_ * H_ * 4;
    bf16* Wt   = (bf16*)wsb;  wsb += (size_t)L_ * 6 * D_ * D_ * 2;      // 84.9 MB (all layers)
    float* qkvb= (float*)wsb; wsb += (size_t)L_ * QKVN_ * 4;      // 110 KB
    int* lengths = (int*)wsb; wsb += 256;

    lengths_kernel<<<1, 256, 0, stream>>>(mask, lengths);
    embed_kernel<<<BT_, 256, 0, stream>>>(batch, tok, pos, x, xb);
    pack_bias<<<(L_ * QKVN_ + 255) / 256, 256, 0, stream>>>(bq, bk, bv, qkvb);
    transpose_w_all<<<dim3(24, 24, 72), dim3(32, 8), 0, stream>>>(Wq, Wk, Wv, Wo, W1, W2, Wt);

    dim3 qkv_g(QKVN_ / 192, BT_P / 256);  // (12, 63)
    dim3 dxd_g(D_ / 192, BT_P / 256);     // (4, 63)
    dim3 feat_g(BT_ / 128, H_, 2);        // (125, 12, 2)
    dim3 kv_g(H_, B_);                    // (12, 64)
    const size_t WS = (size_t)D_ * D_;

    for (int l = 0; l < L_; ++l) {
        const bf16* Wtl = Wt + (size_t)l * 6 * WS;

        // fused QKV: [BT,768] @ [2304,768]^T -> qkv [BT,2304]
        gemm_pipe<<<qkv_g, 512, 0, stream>>>(xb, Wtl, qkvb + l * QKVN_, qkv,
                                             QKVN_, D_, QKVN_, 0, lengths);

        // features (K=64 per head, fused Q+K dispatch)
        feat_kernel<<<feat_g, 256, 0, stream>>>(qkv, omega + (size_t)l * DH_ * F_,
                                                Qf, Kf, lengths);

        // fused KV + Ksum -> transposed bf16 KVt (MFMA batched per (b,h))
        kvsum_kernel<<<kv_g, 256, 0, stream>>>(Kf, qkv + 2 * D_, QKVN_, KVt);

        // attn out via MFMA, written into qkv cols [0,768) (q slice dead after Qf)
        attn_mfma<<<kv_g, 256, 0, stream>>>(Qf, KVt, Z, qkv, QKVN_);

        if (l == L_ - 1)
            attnw_kernel<<<dim3(4, B_ * H_), 256, 0, stream>>>(Qf, Kf, Z, out_attn);

        // Wo proj: reads qkv[:,0:768), writes qkv[:,768:1536)
        gemm_pipe<<<dxd_g, 512, 0, stream>>>(qkv, Wtl + 3 * WS, bo + l * D_, qkv + D_,
                                             D_, QKVN_, QKVN_, 0, lengths);
        ln_kernel<<<BT_, 256, 0, stream>>>(x, qkv + D_, QKVN_, ln1g + l * D_, ln1b + l * D_, xb);

        // FFN1 (GELU): xb @ W1 -> qkv[:,1536:2304)
        gemm_pipe<<<dxd_g, 512, 0, stream>>>(xb, Wtl + 4 * WS, b1 + l * D_, qkv + 2 * D_,
                                             D_, D_, QKVN_, 1, lengths);
        // FFN2: qkv[:,1536:2304) @ W2 -> qkv[:,0:768)
        gemm_pipe<<<dxd_g, 512, 0, stream>>>(qkv + 2 * D_, Wtl + 5 * WS, b2 + l * D_, qkv,
                                             D_, QKVN_, QKVN_, 0, lengths);
        ln_kernel<<<BT_, 256, 0, stream>>>(x, qkv, QKVN_, ln2g + l * D_, ln2b + l * D_, xb);
    }

    cls_kernel<<<(B_ * D_ + 255) / 256, 256, 0, stream>>>(x, out_cls);
}